// Round 1
// baseline (30875.574 us; speedup 1.0000x reference)
//
#include <hip/hip_runtime.h>
#include <cstdint>
#include <cstddef>

// ---------------- constants (from reference) ----------------
constexpr int   Dm    = 1024;
constexpr int   NHn   = 16;
constexpr int   NKVn  = 4;
constexpr int   HDn   = 64;
constexpr int   Ln    = 6;
constexpr int   Sn    = 2048;
constexpr int   Bn    = 2;
constexpr int   ROWS  = Bn * Sn;          // 4096 token rows
constexpr int   VSn   = 50257;
constexpr int   HSn   = 4096;
constexpr float EPSF  = 1.1920929e-07f;
constexpr int   VCHUNK = 4096;            // vocab chunk for LM head

#define DEV __device__ __forceinline__

// ---------------- block reductions (256 threads = 4 waves) ----------------
DEV float block_sum256(float v, float* red) {
#pragma unroll
    for (int off = 32; off; off >>= 1) v += __shfl_xor(v, off);
    __syncthreads();
    if ((threadIdx.x & 63) == 0) red[threadIdx.x >> 6] = v;
    __syncthreads();
    return red[0] + red[1] + red[2] + red[3];
}

DEV float block_max256(float v, float* red) {
#pragma unroll
    for (int off = 32; off; off >>= 1) v = fmaxf(v, __shfl_xor(v, off));
    __syncthreads();
    if ((threadIdx.x & 63) == 0) red[threadIdx.x >> 6] = v;
    __syncthreads();
    return fmaxf(fmaxf(red[0], red[1]), fmaxf(red[2], red[3]));
}

// ---------------- rope tables ----------------
__global__ void rope_kernel(float* __restrict__ cb, float* __restrict__ sb) {
    int idx = blockIdx.x * 256 + threadIdx.x;
    if (idx >= Sn * 32) return;
    int t = idx >> 5, f = idx & 31;
    float freq = powf(10000.f, -(float)f * (1.f / 32.f));
    float ang  = (float)t * freq;
    cb[idx] = cosf(ang);
    sb[idx] = sinf(ang);
}

// ---------------- embedding + rmsn ----------------
__global__ __launch_bounds__(256)
void embed_kernel(const int* __restrict__ ids, const float* __restrict__ ue,
                  const float* __restrict__ be, float* __restrict__ h,
                  float* __restrict__ h0) {
    __shared__ float red[4];
    int r = blockIdx.x;
    int s = r % Sn;
    int id = ids[r];
    int prev = (s == 0) ? 0 : ids[r - 1];
    int bi = ((prev % HSn) * (VSn % HSn) % HSn + id % HSn) % HSn;
    int tid = threadIdx.x;
    float vals[4];
    float ss = 0.f;
#pragma unroll
    for (int t = 0; t < 4; ++t) {
        int j = tid + t * 256;
        float v = (j < 512) ? ue[(size_t)id * 512 + j]
                            : be[(size_t)bi * 512 + (j - 512)];
        vals[t] = v; ss += v * v;
    }
    ss = block_sum256(ss, red);
    float rinv = rsqrtf(ss * (1.f / Dm) + EPSF);
#pragma unroll
    for (int t = 0; t < 4; ++t) {
        int j = tid + t * 256;
        float v = vals[t] * rinv;
        h [(size_t)r * Dm + j] = v;
        h0[(size_t)r * Dm + j] = v;
    }
}

// ---------------- residual mix + rmsn:  x = rm0*x + rm1*x0 ; xn = rmsn(x) ----------------
__global__ __launch_bounds__(256)
void resmix_kernel(float* __restrict__ h, const float* __restrict__ h0,
                   const float* __restrict__ rm0, float* __restrict__ xn) {
    __shared__ float red[4];
    int r = blockIdx.x, tid = threadIdx.x;
    const float* rm1 = rm0 + Dm;
    float vals[4]; float ss = 0.f;
#pragma unroll
    for (int t = 0; t < 4; ++t) {
        int j = tid + t * 256;
        size_t o = (size_t)r * Dm + j;
        float v = rm0[j] * h[o] + rm1[j] * h0[o];
        vals[t] = v; ss += v * v;
        h[o] = v;
    }
    ss = block_sum256(ss, red);
    float rinv = rsqrtf(ss * (1.f / Dm) + EPSF);
#pragma unroll
    for (int t = 0; t < 4; ++t)
        xn[(size_t)r * Dm + tid + t * 256] = vals[t] * rinv;
}

// ---------------- x += sc*y (optional dup copy, optional rmsn out) ----------------
template<bool NORM>
__global__ __launch_bounds__(256)
void axpy_kernel(float* __restrict__ x, const float* __restrict__ y,
                 const float* __restrict__ sc, float* __restrict__ xn,
                 float* __restrict__ dup) {
    __shared__ float red[4];
    int r = blockIdx.x, tid = threadIdx.x;
    float vals[4]; float ss = 0.f;
#pragma unroll
    for (int t = 0; t < 4; ++t) {
        int j = tid + t * 256;
        size_t o = (size_t)r * Dm + j;
        float v = fmaf(sc[j], y[o], x[o]);
        vals[t] = v; ss += v * v;
        x[o] = v;
        if (dup) dup[o] = v;
    }
    if (NORM) {
        ss = block_sum256(ss, red);
        float rinv = rsqrtf(ss * (1.f / Dm) + EPSF);
#pragma unroll
        for (int t = 0; t < 4; ++t)
            xn[(size_t)r * Dm + tid + t * 256] = vals[t] * rinv;
    }
}

// ---------------- standalone rmsn ----------------
__global__ __launch_bounds__(256)
void rmsn_kernel(const float* __restrict__ x, float* __restrict__ out) {
    __shared__ float red[4];
    int r = blockIdx.x, tid = threadIdx.x;
    float vals[4]; float ss = 0.f;
#pragma unroll
    for (int t = 0; t < 4; ++t) {
        float v = x[(size_t)r * Dm + tid + t * 256];
        vals[t] = v; ss += v * v;
    }
    ss = block_sum256(ss, red);
    float rinv = rsqrtf(ss * (1.f / Dm) + EPSF);
#pragma unroll
    for (int t = 0; t < 4; ++t)
        out[(size_t)r * Dm + tid + t * 256] = vals[t] * rinv;
}

// ---------------- SGEMM: C(MxN) = A(MxK) @ B(NxK)^T, epilogue MODE ----------------
// MODE 0: none   MODE 1: relu(v)^2   MODE 2: 30*tanh(v/30)
template<int MODE>
__global__ __launch_bounds__(256)
void gemm_kernel(const float* __restrict__ A, const float* __restrict__ B,
                 float* __restrict__ C, int M, int N, int K,
                 int lda, int ldb, int ldc) {
    __shared__ __align__(16) float As[16][68];   // [k][m], padded
    __shared__ __align__(16) float Bs[16][68];   // [k][n], padded
    const int m0 = blockIdx.x * 64;
    const int n0 = blockIdx.y * 64;
    const int tid = threadIdx.x;
    const int tx = tid & 15, ty = tid >> 4;
    const int r   = tid >> 2;          // 0..63: tile row (A) / tile col (B)
    const int kk4 = (tid & 3) << 2;    // 0,4,8,12

    float acc[4][4] = {{0.f, 0.f, 0.f, 0.f}, {0.f, 0.f, 0.f, 0.f},
                       {0.f, 0.f, 0.f, 0.f}, {0.f, 0.f, 0.f, 0.f}};

    for (int k0 = 0; k0 < K; k0 += 16) {
        float4 av = *(const float4*)(A + (size_t)(m0 + r) * lda + k0 + kk4);
        float4 bv = make_float4(0.f, 0.f, 0.f, 0.f);
        if (n0 + r < N)
            bv = *(const float4*)(B + (size_t)(n0 + r) * ldb + k0 + kk4);
        As[kk4 + 0][r] = av.x; As[kk4 + 1][r] = av.y;
        As[kk4 + 2][r] = av.z; As[kk4 + 3][r] = av.w;
        Bs[kk4 + 0][r] = bv.x; Bs[kk4 + 1][r] = bv.y;
        Bs[kk4 + 2][r] = bv.z; Bs[kk4 + 3][r] = bv.w;
        __syncthreads();
#pragma unroll
        for (int kk = 0; kk < 16; ++kk) {
            float4 a4 = *(const float4*)&As[kk][ty << 2];
            float4 b4 = *(const float4*)&Bs[kk][tx << 2];
            float a[4] = {a4.x, a4.y, a4.z, a4.w};
            float bb[4] = {b4.x, b4.y, b4.z, b4.w};
#pragma unroll
            for (int i = 0; i < 4; ++i)
#pragma unroll
                for (int j = 0; j < 4; ++j)
                    acc[i][j] = fmaf(a[i], bb[j], acc[i][j]);
        }
        __syncthreads();
    }
#pragma unroll
    for (int i = 0; i < 4; ++i) {
        int row = m0 + (ty << 2) + i;
        int col = n0 + (tx << 2);
        float o[4];
#pragma unroll
        for (int j = 0; j < 4; ++j) {
            float v = acc[i][j];
            if (MODE == 1) { v = fmaxf(v, 0.f); v = v * v; }
            else if (MODE == 2) {
                float ax = fabsf(v) * (1.f / 30.f);
                float e  = __expf(-2.f * ax);
                float t  = (1.f - e) / (1.f + e);
                v = copysignf(t * 30.f, v);
            }
            o[j] = v;
        }
        float* cp = C + (size_t)row * ldc + col;
        if (col + 3 < N) {
            *(float4*)cp = make_float4(o[0], o[1], o[2], o[3]);
        } else {
#pragma unroll
            for (int j = 0; j < 4; ++j)
                if (col + j < N) cp[j] = o[j];
        }
    }
}

// ---------------- per-head rmsn + rope (+ optional qg), in place ----------------
// buf rows of 64 floats; row = (b*S + s)*heads + h
__global__ __launch_bounds__(256)
void qknorm_rope_kernel(float* __restrict__ buf, int heads,
                        const float* __restrict__ cosb,
                        const float* __restrict__ sinb,
                        const float* __restrict__ qg) {
    int row  = blockIdx.x * 4 + (threadIdx.x >> 6);
    int lane = threadIdx.x & 63;
    int hh   = row % heads;
    int sidx = (row / heads) % Sn;
    size_t base = (size_t)row * HDn;
    float x = buf[base + lane];
    float ss = x * x;
#pragma unroll
    for (int off = 32; off; off >>= 1) ss += __shfl_xor(ss, off);
    float xn = x * rsqrtf(ss * (1.f / HDn) + EPSF);
    float partner = __shfl_xor(xn, 32);
    int f = lane & 31;
    float c  = cosb[sidx * 32 + f];
    float sv = sinb[sidx * 32 + f];
    // lane<32: x1*c + x2*s ; lane>=32: -x1*s + x2*c
    float out = (lane < 32) ? fmaf(xn, c, partner * sv)
                            : fmaf(xn, c, -partner * sv);
    if (qg) out *= qg[hh];
    buf[base + lane] = out;
}

// ---------------- causal GQA flash attention ----------------
// q layout (B*S, NH*64), k/v layout (B*S, NKV*64). One wave per q row;
// workgroup = 4 consecutive q rows of the same (b, head) -> shared K/V tiles.
__global__ __launch_bounds__(256)
void attn_kernel(const float* __restrict__ qb, const float* __restrict__ kb,
                 const float* __restrict__ vb, float* __restrict__ ob) {
    __shared__ float Ks[64][65];
    __shared__ float Vs[64][65];
    __shared__ float Qs[4][64];
    __shared__ float Ps[4][64];
    const int nqb = Sn / 4;                    // 512 q-blocks per (b,h)
    int wg   = blockIdx.x;
    int qblk = wg % nqb;
    int h    = (wg / nqb) % NHn;
    int b    = wg / (nqb * NHn);
    int kvh  = h >> 2;                         // GQA: group size 4
    int wave = threadIdx.x >> 6;
    int lane = threadIdx.x & 63;
    int qi   = qblk * 4 + wave;
    size_t qoff = (size_t)(b * Sn + qi) * Dm + h * HDn + lane;
    Qs[wave][lane] = qb[qoff];
    float mrun = -INFINITY, lrun = 0.f, acc = 0.f;
    int nblk = (qblk * 4 + 3) / 64 + 1;        // same for all 4 waves
    for (int kbk = 0; kbk < nblk; ++kbk) {
        __syncthreads();                       // prev-iter reads done / Qs visible
        for (int idx = threadIdx.x; idx < 1024; idx += 256) {
            int j  = idx >> 4;
            int d4 = (idx & 15) << 2;
            size_t g = (size_t)(b * Sn + kbk * 64 + j) * (NKVn * HDn) + kvh * HDn + d4;
            float4 k4 = *(const float4*)(kb + g);
            Ks[j][d4 + 0] = k4.x; Ks[j][d4 + 1] = k4.y;
            Ks[j][d4 + 2] = k4.z; Ks[j][d4 + 3] = k4.w;
            float4 v4 = *(const float4*)(vb + g);
            Vs[j][d4 + 0] = v4.x; Vs[j][d4 + 1] = v4.y;
            Vs[j][d4 + 2] = v4.z; Vs[j][d4 + 3] = v4.w;
        }
        __syncthreads();
        // lane = key index within block
        float sc = 0.f;
#pragma unroll 16
        for (int d = 0; d < 64; ++d)
            sc = fmaf(Qs[wave][d], Ks[lane][d], sc);
        sc *= 0.125f;                          // 1/sqrt(64)
        int jg = kbk * 64 + lane;
        if (jg > qi) sc = -INFINITY;
        float mb = sc;
#pragma unroll
        for (int off = 32; off; off >>= 1)
            mb = fmaxf(mb, __shfl_xor(mb, off));
        float mnew = fmaxf(mrun, mb);
        float p = __expf(sc - mnew);
        float psum = p;
#pragma unroll
        for (int off = 32; off; off >>= 1)
            psum += __shfl_xor(psum, off);
        float resc = __expf(mrun - mnew);
        lrun = lrun * resc + psum;
        Ps[wave][lane] = p;
        __syncthreads();
        // lane = head dim
        float a = 0.f;
#pragma unroll 16
        for (int j = 0; j < 64; ++j)
            a = fmaf(Ps[wave][j], Vs[j][lane], a);
        acc = acc * resc + a;
        mrun = mnew;
    }
    ob[qoff] = acc / lrun;
}

// ---------------- LM head loss reductions ----------------
__global__ void loss_init_kernel(float* __restrict__ m, float* __restrict__ s,
                                 float* __restrict__ tg) {
    int i = blockIdx.x * 256 + threadIdx.x;
    if (i < ROWS) { m[i] = -INFINITY; s[i] = 0.f; tg[i] = 0.f; }
}

__global__ __launch_bounds__(256)
void chunk_reduce_kernel(const float* __restrict__ Cc, int Nc, int c0,
                         const int* __restrict__ y, float* __restrict__ m,
                         float* __restrict__ s, float* __restrict__ tg) {
    __shared__ float red[4];
    int r = blockIdx.x, tid = threadIdx.x;
    const float* row = Cc + (size_t)r * VCHUNK;
    float mx = -INFINITY;
    for (int j = tid; j < Nc; j += 256) mx = fmaxf(mx, row[j]);
    mx = block_max256(mx, red);
    float se = 0.f;
    for (int j = tid; j < Nc; j += 256) se += __expf(row[j] - mx);
    se = block_sum256(se, red);
    if (tid == 0) {
        float mo = m[r];
        float mn = fmaxf(mo, mx);
        s[r] = s[r] * __expf(mo - mn) + se * __expf(mx - mn);
        m[r] = mn;
        int t = y[r] - c0;
        if (t >= 0 && t < Nc) tg[r] = row[t];
    }
}

__global__ __launch_bounds__(256)
void loss_final_kernel(const float* __restrict__ m, const float* __restrict__ s,
                       const float* __restrict__ tg, float* __restrict__ out) {
    __shared__ float red[4];
    float part = 0.f;
    for (int r = threadIdx.x; r < ROWS; r += 256)
        part += m[r] + logf(s[r]) - tg[r];
    part = block_sum256(part, red);
    if (threadIdx.x == 0) out[0] = part * (1.f / ROWS);
}

// ---------------- host orchestration ----------------
extern "C" void kernel_launch(void* const* d_in, const int* in_sizes, int n_in,
                              void* d_out, int out_size, void* d_ws, size_t ws_size,
                              hipStream_t stream) {
    const int*   ids = (const int*)d_in[0];
    const int*   yv  = (const int*)d_in[1];
    const float* ue  = (const float*)d_in[2];
    const float* be  = (const float*)d_in[3];
    const float* Wq  = (const float*)d_in[4];
    const float* Wk  = (const float*)d_in[5];
    const float* Wv  = (const float*)d_in[6];
    const float* Wo  = (const float*)d_in[7];
    const float* qg  = (const float*)d_in[8];
    const float* asc = (const float*)d_in[9];
    const float* msc = (const float*)d_in[10];
    const float* rm  = (const float*)d_in[11];
    const float* Wf  = (const float*)d_in[12];
    const float* Wo2 = (const float*)d_in[13];
    const float* sw  = (const float*)d_in[14];
    (void)in_sizes; (void)n_in; (void)out_size; (void)ws_size;

    char* wsb = (char*)d_ws;
    size_t off = 0;
    auto alloc = [&](size_t nfloats) {
        float* p = (float*)(wsb + off);
        off += ((nfloats * sizeof(float) + 255) & ~size_t(255));
        return p;
    };
    float* h     = alloc((size_t)ROWS * Dm);
    float* h0    = alloc((size_t)ROWS * Dm);
    float* xn    = alloc((size_t)ROWS * Dm);
    float* qbuf  = alloc((size_t)ROWS * Dm);
    float* kbuf  = alloc((size_t)ROWS * NKVn * HDn);
    float* vbuf  = alloc((size_t)ROWS * NKVn * HDn);
    float* att   = alloc((size_t)ROWS * Dm);
    float* proj  = alloc((size_t)ROWS * Dm);
    float* hid   = alloc((size_t)ROWS * 3 * Dm);
    float* skb   = alloc((size_t)Ln * ROWS * Dm);
    float* cosb  = alloc((size_t)Sn * 32);
    float* sinb  = alloc((size_t)Sn * 32);
    float* chunk = alloc((size_t)ROWS * VCHUNK);
    float* mrow  = alloc(ROWS);
    float* srow  = alloc(ROWS);
    float* tgv   = alloc(ROWS);

    rope_kernel<<<(Sn * 32 + 255) / 256, 256, 0, stream>>>(cosb, sinb);
    embed_kernel<<<ROWS, 256, 0, stream>>>(ids, ue, be, h, h0);

    auto gemm = [&](int mode, const float* A, const float* Bm, float* Cm,
                    int M, int N, int K, int lda, int ldb, int ldc) {
        dim3 g(M / 64, (N + 63) / 64);
        if (mode == 0)
            gemm_kernel<0><<<g, 256, 0, stream>>>(A, Bm, Cm, M, N, K, lda, ldb, ldc);
        else if (mode == 1)
            gemm_kernel<1><<<g, 256, 0, stream>>>(A, Bm, Cm, M, N, K, lda, ldb, ldc);
        else
            gemm_kernel<2><<<g, 256, 0, stream>>>(A, Bm, Cm, M, N, K, lda, ldb, ldc);
    };

    auto run_block = [&](int l, float* dup) {
        resmix_kernel<<<ROWS, 256, 0, stream>>>(h, h0, rm + (size_t)l * 2 * Dm, xn);
        gemm(0, xn, Wq + (size_t)l * Dm * Dm,      qbuf, ROWS, Dm,   Dm,     Dm,     Dm,     Dm);
        gemm(0, xn, Wk + (size_t)l * 256 * Dm,     kbuf, ROWS, 256,  Dm,     Dm,     Dm,     256);
        gemm(0, xn, Wv + (size_t)l * 256 * Dm,     vbuf, ROWS, 256,  Dm,     Dm,     Dm,     256);
        qknorm_rope_kernel<<<ROWS * NHn / 4, 256, 0, stream>>>(qbuf, NHn, cosb, sinb,
                                                               qg + (size_t)l * NHn);
        qknorm_rope_kernel<<<ROWS * NKVn / 4, 256, 0, stream>>>(kbuf, NKVn, cosb, sinb,
                                                                nullptr);
        attn_kernel<<<Bn * NHn * (Sn / 4), 256, 0, stream>>>(qbuf, kbuf, vbuf, att);
        gemm(0, att, Wo + (size_t)l * Dm * Dm,     proj, ROWS, Dm,   Dm,     Dm,     Dm,     Dm);
        axpy_kernel<true><<<ROWS, 256, 0, stream>>>(h, proj, asc + (size_t)l * Dm, xn, nullptr);
        gemm(1, xn, Wf + (size_t)l * 3 * Dm * Dm,  hid,  ROWS, 3*Dm, Dm,     Dm,     Dm,     3*Dm);
        gemm(0, hid, Wo2 + (size_t)l * 3 * Dm * Dm, proj, ROWS, Dm,  3*Dm,   3*Dm,   3*Dm,   Dm);
        axpy_kernel<false><<<ROWS, 256, 0, stream>>>(h, proj, msc + (size_t)l * Dm, nullptr, dup);
    };

    // forward pass 1: collect skips
    for (int l = 0; l < Ln; ++l)
        run_block(l, skb + (size_t)l * ROWS * Dm);
    // reverse pass with skip adds
    for (int i = 0; i < Ln; ++i) {
        int j = Ln - 1 - i;
        axpy_kernel<false><<<ROWS, 256, 0, stream>>>(h, skb + (size_t)j * ROWS * Dm,
                                                     sw + (size_t)i * Dm, nullptr, nullptr);
        run_block(j, nullptr);
    }

    // final norm + LM head (chunked online log-softmax)
    rmsn_kernel<<<ROWS, 256, 0, stream>>>(h, xn);
    loss_init_kernel<<<(ROWS + 255) / 256, 256, 0, stream>>>(mrow, srow, tgv);
    for (int c0 = 0; c0 < VSn; c0 += VCHUNK) {
        int Nc = (VSn - c0 < VCHUNK) ? (VSn - c0) : VCHUNK;
        gemm(2, xn, ue + (size_t)c0 * 512, chunk, ROWS, Nc, 512, Dm, 512, VCHUNK);
        chunk_reduce_kernel<<<ROWS, 256, 0, stream>>>(chunk, Nc, c0, yv, mrow, srow, tgv);
    }
    loss_final_kernel<<<1, 256, 0, stream>>>(mrow, srow, tgv, (float*)d_out);
}

// Round 3
// 5278.162 us; speedup vs baseline: 5.8497x; 5.8497x over previous
//
#include <hip/hip_runtime.h>
#include <cstdint>
#include <cstddef>

// ---------------- constants (from reference) ----------------
constexpr int   Dm    = 1024;
constexpr int   NHn   = 16;
constexpr int   NKVn  = 4;
constexpr int   HDn   = 64;
constexpr int   Ln    = 6;
constexpr int   Sn    = 2048;
constexpr int   Bn    = 2;
constexpr int   ROWS  = Bn * Sn;          // 4096 token rows
constexpr int   VSn   = 50257;
constexpr int   HSn   = 4096;
constexpr float EPSF  = 1.1920929e-07f;
constexpr int   VCHUNK = 4096;            // vocab chunk for LM head
constexpr int   VPAD   = 50304;           // 393*128

#define DEV __device__ __forceinline__

typedef __attribute__((ext_vector_type(8))) short bf16x8;
typedef __attribute__((ext_vector_type(4))) float f32x4;

DEV unsigned short f2bf(float f) {
    unsigned int u = __float_as_uint(f);
    u = (u + 0x7fffu + ((u >> 16) & 1u)) >> 16;
    return (unsigned short)u;
}

DEV float b2f(unsigned short v) {
    return __uint_as_float(((unsigned int)v) << 16);
}

DEV f32x4 mfma16(bf16x8 a, bf16x8 b, f32x4 c) {
    return __builtin_amdgcn_mfma_f32_16x16x32_bf16(a, b, c, 0, 0, 0);
}

DEV void llds16(const unsigned short* g, unsigned short* l) {
    __builtin_amdgcn_global_load_lds(
        (const __attribute__((address_space(1))) void*)g,
        (__attribute__((address_space(3))) void*)l, 16, 0, 0);
}

// ---------------- block reductions (256 threads = 4 waves) ----------------
DEV float block_sum256(float v, float* red) {
#pragma unroll
    for (int off = 32; off; off >>= 1) v += __shfl_xor(v, off);
    __syncthreads();
    if ((threadIdx.x & 63) == 0) red[threadIdx.x >> 6] = v;
    __syncthreads();
    return red[0] + red[1] + red[2] + red[3];
}

DEV float block_max256(float v, float* red) {
#pragma unroll
    for (int off = 32; off; off >>= 1) v = fmaxf(v, __shfl_xor(v, off));
    __syncthreads();
    if ((threadIdx.x & 63) == 0) red[threadIdx.x >> 6] = v;
    __syncthreads();
    return fmaxf(fmaxf(red[0], red[1]), fmaxf(red[2], red[3]));
}

// ---------------- rope tables ----------------
__global__ void rope_kernel(float* __restrict__ cb, float* __restrict__ sb) {
    int idx = blockIdx.x * 256 + threadIdx.x;
    if (idx >= Sn * 32) return;
    int t = idx >> 5, f = idx & 31;
    float freq = powf(10000.f, -(float)f * (1.f / 32.f));
    float ang  = (float)t * freq;
    cb[idx] = cosf(ang);
    sb[idx] = sinf(ang);
}

// ---------------- fp32 -> bf16 convert / zero pad ----------------
__global__ void cvt_bf16_kernel(const float* __restrict__ s, unsigned short* __restrict__ d, int n4) {
    int i = blockIdx.x * 256 + threadIdx.x;
    if (i >= n4) return;
    float4 v = *(const float4*)(s + (size_t)i * 4);
    ushort4 o;
    o.x = f2bf(v.x); o.y = f2bf(v.y); o.z = f2bf(v.z); o.w = f2bf(v.w);
    *(ushort4*)(d + (size_t)i * 4) = o;
}

__global__ void zpad_kernel(unsigned short* __restrict__ p, int n) {
    int i = blockIdx.x * 256 + threadIdx.x;
    if (i < n) p[i] = 0;
}

// ---------------- embedding + rmsn ----------------
__global__ __launch_bounds__(256)
void embed_kernel(const int* __restrict__ ids, const float* __restrict__ ue,
                  const float* __restrict__ be, float* __restrict__ h,
                  float* __restrict__ h0) {
    __shared__ float red[4];
    int r = blockIdx.x;
    int s = r % Sn;
    int id = ids[r];
    int prev = (s == 0) ? 0 : ids[r - 1];
    int bi = ((prev % HSn) * (VSn % HSn) % HSn + id % HSn) % HSn;
    int tid = threadIdx.x;
    float vals[4];
    float ss = 0.f;
#pragma unroll
    for (int t = 0; t < 4; ++t) {
        int j = tid + t * 256;
        float v = (j < 512) ? ue[(size_t)id * 512 + j]
                            : be[(size_t)bi * 512 + (j - 512)];
        vals[t] = v; ss += v * v;
    }
    ss = block_sum256(ss, red);
    float rinv = rsqrtf(ss * (1.f / Dm) + EPSF);
#pragma unroll
    for (int t = 0; t < 4; ++t) {
        int j = tid + t * 256;
        float v = vals[t] * rinv;
        h [(size_t)r * Dm + j] = v;
        h0[(size_t)r * Dm + j] = v;
    }
}

// ---------------- residual mix + rmsn -> bf16 ----------------
__global__ __launch_bounds__(256)
void resmix_kernel(float* __restrict__ h, const float* __restrict__ h0,
                   const float* __restrict__ rm0, unsigned short* __restrict__ xnb) {
    __shared__ float red[4];
    int r = blockIdx.x, tid = threadIdx.x;
    const float* rm1 = rm0 + Dm;
    float vals[4]; float ss = 0.f;
#pragma unroll
    for (int t = 0; t < 4; ++t) {
        int j = tid + t * 256;
        size_t o = (size_t)r * Dm + j;
        float v = rm0[j] * h[o] + rm1[j] * h0[o];
        vals[t] = v; ss += v * v;
        h[o] = v;
    }
    ss = block_sum256(ss, red);
    float rinv = rsqrtf(ss * (1.f / Dm) + EPSF);
#pragma unroll
    for (int t = 0; t < 4; ++t)
        xnb[(size_t)r * Dm + tid + t * 256] = f2bf(vals[t] * rinv);
}

// ---------------- x += sc*y (optional dup copy, optional bf16 rmsn out) ----------------
template<bool NORM>
__global__ __launch_bounds__(256)
void axpy_kernel(float* __restrict__ x, const float* __restrict__ y,
                 const float* __restrict__ sc, unsigned short* __restrict__ xnb,
                 float* __restrict__ dup) {
    __shared__ float red[4];
    int r = blockIdx.x, tid = threadIdx.x;
    float vals[4]; float ss = 0.f;
#pragma unroll
    for (int t = 0; t < 4; ++t) {
        int j = tid + t * 256;
        size_t o = (size_t)r * Dm + j;
        float v = fmaf(sc[j], y[o], x[o]);
        vals[t] = v; ss += v * v;
        x[o] = v;
        if (dup) dup[o] = v;
    }
    if (NORM) {
        ss = block_sum256(ss, red);
        float rinv = rsqrtf(ss * (1.f / Dm) + EPSF);
#pragma unroll
        for (int t = 0; t < 4; ++t)
            xnb[(size_t)r * Dm + tid + t * 256] = f2bf(vals[t] * rinv);
    }
}

// ---------------- standalone rmsn -> bf16 ----------------
__global__ __launch_bounds__(256)
void rmsn_kernel(const float* __restrict__ x, unsigned short* __restrict__ out) {
    __shared__ float red[4];
    int r = blockIdx.x, tid = threadIdx.x;
    float vals[4]; float ss = 0.f;
#pragma unroll
    for (int t = 0; t < 4; ++t) {
        float v = x[(size_t)r * Dm + tid + t * 256];
        vals[t] = v; ss += v * v;
    }
    ss = block_sum256(ss, red);
    float rinv = rsqrtf(ss * (1.f / Dm) + EPSF);
#pragma unroll
    for (int t = 0; t < 4; ++t)
        out[(size_t)r * Dm + tid + t * 256] = f2bf(vals[t] * rinv);
}

// ---------------- bf16 MFMA GEMM: C(MxN) = A(MxK) @ B(NxK)^T ----------------
// MODE 0: none   MODE 1: relu^2   MODE 2: 30*tanh(v/30).  M,N mult of 128, K mult of 32.
template<int MODE, bool BF16OUT>
__global__ __launch_bounds__(256)
void gemm_bf16_kernel(const unsigned short* __restrict__ A,
                      const unsigned short* __restrict__ B,
                      void* __restrict__ Cv, int M, int N, int K,
                      int lda, int ldb, int ldc) {
    __shared__ __align__(16) unsigned short As[128 * 32];
    __shared__ __align__(16) unsigned short Bs[128 * 32];
    const int m0 = blockIdx.x * 128, n0 = blockIdx.y * 128;
    const int tid  = threadIdx.x;
    const int w    = tid >> 6, lane = tid & 63;
    const int l15  = lane & 15, quad = lane >> 4;
    const int wr   = w >> 1, wc = w & 1;

    // staging: wave w covers rows w*32 .. w*32+31 (2 loads of 16 rows)
    const int srow = lane >> 2, sch = lane & 3;
    const unsigned short* Ag = A + (size_t)(m0 + w * 32 + srow) * lda + sch * 8;
    const unsigned short* Bg = B + (size_t)(n0 + w * 32 + srow) * ldb + sch * 8;
    unsigned short* AsW = As + w * 1024;
    unsigned short* BsW = Bs + w * 1024;

    f32x4 acc[4][4] = {};

    for (int k0 = 0; k0 < K; k0 += 32) {
        __syncthreads();
        llds16(Ag + k0,             AsW);
        llds16(Ag + k0 + 16 * lda,  AsW + 512);
        llds16(Bg + k0,             BsW);
        llds16(Bg + k0 + 16 * ldb,  BsW + 512);
        __syncthreads();
        bf16x8 af[4], bfv[4];
#pragma unroll
        for (int i = 0; i < 4; ++i)
            af[i] = *(const bf16x8*)&As[(wr * 64 + i * 16 + l15) * 32 + quad * 8];
#pragma unroll
        for (int j = 0; j < 4; ++j)
            bfv[j] = *(const bf16x8*)&Bs[(wc * 64 + j * 16 + l15) * 32 + quad * 8];
#pragma unroll
        for (int i = 0; i < 4; ++i)
#pragma unroll
            for (int j = 0; j < 4; ++j)
                acc[i][j] = mfma16(af[i], bfv[j], acc[i][j]);
    }

#pragma unroll
    for (int i = 0; i < 4; ++i) {
#pragma unroll
        for (int j = 0; j < 4; ++j) {
            int row = m0 + wr * 64 + i * 16 + quad * 4;
            int col = n0 + wc * 64 + j * 16 + l15;
#pragma unroll
            for (int r = 0; r < 4; ++r) {
                float v = acc[i][j][r];
                if (MODE == 1) { v = fmaxf(v, 0.f); v = v * v; }
                else if (MODE == 2) {
                    float ax = fabsf(v) * (1.f / 30.f);
                    float e  = __expf(-2.f * ax);
                    float t  = (1.f - e) / (1.f + e);
                    v = copysignf(t * 30.f, v);
                }
                if (BF16OUT)
                    ((unsigned short*)Cv)[(size_t)(row + r) * ldc + col] = f2bf(v);
                else
                    ((float*)Cv)[(size_t)(row + r) * ldc + col] = v;
            }
        }
    }
}

// ---------------- per-head rmsn + rope -> bf16 (bf16 input) ----------------
// in: bf16 rows [token][in_ld], head block at in_off + hh*64
// out: bf16 rows [token][out_ld], head block at hh*64.  scale folded for q.
__global__ __launch_bounds__(256)
void qknorm_rope_kernel(const unsigned short* __restrict__ in, int in_ld, int in_off,
                        unsigned short* __restrict__ out, int out_ld, int heads,
                        const float* __restrict__ cosb, const float* __restrict__ sinb,
                        const float* __restrict__ qg, float scale) {
    int row  = blockIdx.x * 4 + (threadIdx.x >> 6);   // token*heads + hh
    int lane = threadIdx.x & 63;
    int hh   = row % heads;
    int t    = row / heads;
    int sidx = t % Sn;
    float x = b2f(in[(size_t)t * in_ld + in_off + hh * 64 + lane]);
    float ss = x * x;
#pragma unroll
    for (int off = 32; off; off >>= 1) ss += __shfl_xor(ss, off);
    float xn = x * rsqrtf(ss * (1.f / HDn) + EPSF);
    float partner = __shfl_xor(xn, 32);
    int f = lane & 31;
    float c  = cosb[sidx * 32 + f];
    float sv = sinb[sidx * 32 + f];
    float o = (lane < 32) ? fmaf(xn, c, partner * sv)
                          : fmaf(xn, c, -partner * sv);
    if (qg) o *= qg[hh] * scale;
    out[(size_t)t * out_ld + hh * 64 + lane] = f2bf(o);
}

// ---------------- V transpose: bf16 [4096][in_ld] (cols off..off+255) -> bf16 [256][4096] ----------------
__global__ __launch_bounds__(256)
void vtrans_kernel(const unsigned short* __restrict__ in, int in_ld, int in_off,
                   unsigned short* __restrict__ out) {
    __shared__ unsigned short tile[32][33];
    int s0 = blockIdx.x * 32;
    int c0 = blockIdx.y * 32;
    int i = threadIdx.x >> 5;
    int j = threadIdx.x & 31;
#pragma unroll
    for (int k = 0; k < 4; ++k)
        tile[i + k * 8][j] = in[(size_t)(s0 + i + k * 8) * in_ld + in_off + c0 + j];
    __syncthreads();
#pragma unroll
    for (int k = 0; k < 4; ++k)
        out[(size_t)(c0 + i + k * 8) * (size_t)ROWS + s0 + j] = tile[j][i + k * 8];
}

// ---------------- causal GQA flash attention, bf16 MFMA ----------------
// qb: bf16 [token][1024] (qg & 1/8 folded), kb: bf16 [token][256],
// vt: bf16 [256][4096] (transposed), ob: bf16 [token][1024].
// One wg = 64 q rows of one (b, h); wave w = 16 q rows.
__global__ __launch_bounds__(256)
void attn_mfma_kernel(const unsigned short* __restrict__ qb,
                      const unsigned short* __restrict__ kb,
                      const unsigned short* __restrict__ vt,
                      unsigned short* __restrict__ ob) {
    __shared__ __align__(16) unsigned short Ks[64 * 72];
    __shared__ __align__(16) unsigned short Vs[64 * 72];
    __shared__ __align__(16) unsigned short Ps[64 * 72];
    const int tile = blockIdx.x & 31;
    const int h    = (blockIdx.x >> 5) & 15;
    const int b    = blockIdx.x >> 9;
    const int kvh  = h >> 2;
    const int w    = threadIdx.x >> 6, lane = threadIdx.x & 63;
    const int l15  = lane & 15, quad = lane >> 4;
    const int q0   = tile * 64;

    // Q fragments (constant across kv blocks)
    const size_t qrow = (size_t)(b * Sn + q0 + w * 16 + l15) * 1024 + h * 64;
    bf16x8 qf0 = *(const bf16x8*)(qb + qrow + quad * 8);
    bf16x8 qf1 = *(const bf16x8*)(qb + qrow + 32 + quad * 8);

    f32x4 Oacc[4] = {};
    float mrow[4] = {-INFINITY, -INFINITY, -INFINITY, -INFINITY};
    float lrow[4] = {0.f, 0.f, 0.f, 0.f};
    const int qbase = q0 + w * 16 + quad * 4;   // + r

    const int nblk = tile + 1;
    for (int kb_i = 0; kb_i < nblk; ++kb_i) {
        const int k0 = kb_i * 64;
        __syncthreads();
        // stage K [key][d] and Vt [d][key], padded rows of 72 elems
        {
            const size_t kgb = (size_t)(b * Sn + k0) * 256 + kvh * 64;
            const size_t vgb = (size_t)(kvh * 64) * (size_t)ROWS + b * Sn + k0;
#pragma unroll
            for (int ii = 0; ii < 2; ++ii) {
                int idx = threadIdx.x + ii * 256;
                int rr = idx >> 3, ch = idx & 7;
                uint4 kvl = *(const uint4*)(kb + kgb + (size_t)rr * 256 + ch * 8);
                *(uint4*)&Ks[rr * 72 + ch * 8] = kvl;
                uint4 vvl = *(const uint4*)(vt + vgb + (size_t)rr * (size_t)ROWS + ch * 8);
                *(uint4*)&Vs[rr * 72 + ch * 8] = vvl;
            }
        }
        __syncthreads();

        // QK^T: S[c] = 16q x 16k tile c
        f32x4 S[4] = {};
#pragma unroll
        for (int c = 0; c < 4; ++c) {
            bf16x8 kf0 = *(const bf16x8*)&Ks[(c * 16 + l15) * 72 + quad * 8];
            bf16x8 kf1 = *(const bf16x8*)&Ks[(c * 16 + l15) * 72 + 32 + quad * 8];
            S[c] = mfma16(qf0, kf0, S[c]);
            S[c] = mfma16(qf1, kf1, S[c]);
        }

        // mask + online softmax (rows quad*4+r, cols c*16+l15)
        float rmax[4] = {-INFINITY, -INFINITY, -INFINITY, -INFINITY};
#pragma unroll
        for (int c = 0; c < 4; ++c) {
            int key = k0 + c * 16 + l15;
#pragma unroll
            for (int r = 0; r < 4; ++r) {
                float sv = S[c][r];
                if (key > qbase + r) sv = -INFINITY;
                S[c][r] = sv;
                rmax[r] = fmaxf(rmax[r], sv);
            }
        }
#pragma unroll
        for (int m = 1; m <= 8; m <<= 1)
#pragma unroll
            for (int r = 0; r < 4; ++r)
                rmax[r] = fmaxf(rmax[r], __shfl_xor(rmax[r], m));
        float alpha[4], lsum[4];
#pragma unroll
        for (int r = 0; r < 4; ++r) {
            float mn = fmaxf(mrow[r], rmax[r]);
            alpha[r] = __expf(mrow[r] - mn);
            mrow[r] = mn; lsum[r] = 0.f;
        }
#pragma unroll
        for (int c = 0; c < 4; ++c)
#pragma unroll
            for (int r = 0; r < 4; ++r) {
                float p = __expf(S[c][r] - mrow[r]);
                S[c][r] = p; lsum[r] += p;
            }
#pragma unroll
        for (int m = 1; m <= 8; m <<= 1)
#pragma unroll
            for (int r = 0; r < 4; ++r)
                lsum[r] += __shfl_xor(lsum[r], m);
#pragma unroll
        for (int r = 0; r < 4; ++r)
            lrow[r] = lrow[r] * alpha[r] + lsum[r];
#pragma unroll
        for (int dt = 0; dt < 4; ++dt)
#pragma unroll
            for (int r = 0; r < 4; ++r)
                Oacc[dt][r] *= alpha[r];

        // P -> LDS (wave-private region), A-operand layout [q][key]
#pragma unroll
        for (int c = 0; c < 4; ++c)
#pragma unroll
            for (int r = 0; r < 4; ++r)
                Ps[(w * 16 + quad * 4 + r) * 72 + c * 16 + l15] = f2bf(S[c][r]);

        // PV: O[16q][64d] += P @ V
        bf16x8 pf0 = *(const bf16x8*)&Ps[(w * 16 + l15) * 72 + quad * 8];
        bf16x8 pf1 = *(const bf16x8*)&Ps[(w * 16 + l15) * 72 + 32 + quad * 8];
#pragma unroll
        for (int dt = 0; dt < 4; ++dt) {
            bf16x8 vf0 = *(const bf16x8*)&Vs[(dt * 16 + l15) * 72 + quad * 8];
            bf16x8 vf1 = *(const bf16x8*)&Vs[(dt * 16 + l15) * 72 + 32 + quad * 8];
            Oacc[dt] = mfma16(pf0, vf0, Oacc[dt]);
            Oacc[dt] = mfma16(pf1, vf1, Oacc[dt]);
        }
    }

    // epilogue
#pragma unroll
    for (int dt = 0; dt < 4; ++dt)
#pragma unroll
        for (int r = 0; r < 4; ++r) {
            size_t o = (size_t)(b * Sn + qbase + r) * 1024 + h * 64 + dt * 16 + l15;
            ob[o] = f2bf(Oacc[dt][r] / lrow[r]);
        }
}

// ---------------- LM head loss reductions ----------------
__global__ void loss_init_kernel(float* __restrict__ m, float* __restrict__ s,
                                 float* __restrict__ tg) {
    int i = blockIdx.x * 256 + threadIdx.x;
    if (i < ROWS) { m[i] = -INFINITY; s[i] = 0.f; tg[i] = 0.f; }
}

__global__ __launch_bounds__(256)
void chunk_reduce_kernel(const float* __restrict__ Cc, int Nc, int c0,
                         const int* __restrict__ y, float* __restrict__ m,
                         float* __restrict__ s, float* __restrict__ tg) {
    __shared__ float red[4];
    int r = blockIdx.x, tid = threadIdx.x;
    const float* row = Cc + (size_t)r * VCHUNK;
    float mx = -INFINITY;
    for (int j = tid; j < Nc; j += 256) mx = fmaxf(mx, row[j]);
    mx = block_max256(mx, red);
    float se = 0.f;
    for (int j = tid; j < Nc; j += 256) se += __expf(row[j] - mx);
    se = block_sum256(se, red);
    if (tid == 0) {
        float mo = m[r];
        float mn = fmaxf(mo, mx);
        s[r] = s[r] * __expf(mo - mn) + se * __expf(mx - mn);
        m[r] = mn;
        int t = y[r] - c0;
        if (t >= 0 && t < Nc) tg[r] = row[t];
    }
}

__global__ __launch_bounds__(256)
void loss_final_kernel(const float* __restrict__ m, const float* __restrict__ s,
                       const float* __restrict__ tg, float* __restrict__ out) {
    __shared__ float red[4];
    float part = 0.f;
    for (int r = threadIdx.x; r < ROWS; r += 256)
        part += m[r] + logf(s[r]) - tg[r];
    part = block_sum256(part, red);
    if (threadIdx.x == 0) out[0] = part * (1.f / ROWS);
}

// ---------------- host orchestration ----------------
extern "C" void kernel_launch(void* const* d_in, const int* in_sizes, int n_in,
                              void* d_out, int out_size, void* d_ws, size_t ws_size,
                              hipStream_t stream) {
    const int*   ids = (const int*)d_in[0];
    const int*   yv  = (const int*)d_in[1];
    const float* ue  = (const float*)d_in[2];
    const float* be  = (const float*)d_in[3];
    const float* Wq  = (const float*)d_in[4];
    const float* Wk  = (const float*)d_in[5];
    const float* Wv  = (const float*)d_in[6];
    const float* Wo  = (const float*)d_in[7];
    const float* qg  = (const float*)d_in[8];
    const float* asc = (const float*)d_in[9];
    const float* msc = (const float*)d_in[10];
    const float* rm  = (const float*)d_in[11];
    const float* Wf  = (const float*)d_in[12];
    const float* Wo2 = (const float*)d_in[13];
    const float* sw  = (const float*)d_in[14];
    (void)in_sizes; (void)n_in; (void)out_size; (void)ws_size;

    char* wsb = (char*)d_ws;
    size_t off = 0;
    auto alloc = [&](size_t bytes) {
        void* p = (void*)(wsb + off);
        off += ((bytes + 255) & ~size_t(255));
        return p;
    };
    // fp32  (total ws budget ~277 MB; round-1's 312 MB fit, round-2's 443 MB crashed)
    float* h    = (float*)alloc((size_t)ROWS * Dm * 4);                // 16 MB
    float* h0   = (float*)alloc((size_t)ROWS * Dm * 4);                // 16 MB
    float* proj = (float*)alloc((size_t)ROWS * Dm * 4);                // 16 MB
    float* skb  = (float*)alloc((size_t)Ln * ROWS * Dm * 4);           // 96 MB
    float* cosb = (float*)alloc((size_t)Sn * 32 * 4);
    float* sinb = (float*)alloc((size_t)Sn * 32 * 4);
    float* mrow = (float*)alloc(ROWS * 4);
    float* srow = (float*)alloc(ROWS * 4);
    float* tgv  = (float*)alloc(ROWS * 4);
    // chunk (64 MB) aliases skb: skips are dead by the time the LM head runs
    float* chunk = skb;
    // bf16
    unsigned short* xnb   = (unsigned short*)alloc((size_t)ROWS * Dm * 2);       // 8 MB
    unsigned short* qkvb  = (unsigned short*)alloc((size_t)ROWS * 1536 * 2);     // 12 MB
    unsigned short* qbf   = (unsigned short*)alloc((size_t)ROWS * Dm * 2);       // 8 MB
    unsigned short* kbf   = (unsigned short*)alloc((size_t)ROWS * 256 * 2);      // 2 MB
    unsigned short* vtb   = (unsigned short*)alloc((size_t)256 * ROWS * 2);      // 2 MB
    unsigned short* attb  = (unsigned short*)alloc((size_t)ROWS * Dm * 2);       // 8 MB
    unsigned short* hidb  = (unsigned short*)alloc((size_t)ROWS * 3 * Dm * 2);   // 24 MB
    unsigned short* wbuf  = (unsigned short*)alloc((size_t)8704 * 1024 * 2);     // 17.8 MB (per-layer)
    unsigned short* ueb   = (unsigned short*)alloc((size_t)VPAD * 512 * 2);      // 51.5 MB

    // per-layer weight staging offsets (elements)
    unsigned short* wqkvb = wbuf;                          // 1536*1024
    unsigned short* wob   = wbuf + (size_t)1536 * 1024;    // 1024*1024
    unsigned short* wfb   = wbuf + (size_t)2560 * 1024;    // 3072*1024
    unsigned short* wo2b  = wbuf + (size_t)5632 * 1024;    // 3072*1024

    auto cvt = [&](const float* s, unsigned short* d, size_t n) {
        int n4 = (int)(n / 4);
        cvt_bf16_kernel<<<(n4 + 255) / 256, 256, 0, stream>>>(s, d, n4);
    };

    // one-time conversions
    cvt(ue, ueb, (size_t)VSn * 512);
    zpad_kernel<<<((VPAD - VSn) * 512 + 255) / 256, 256, 0, stream>>>(
        ueb + (size_t)VSn * 512, (VPAD - VSn) * 512);

    rope_kernel<<<(Sn * 32 + 255) / 256, 256, 0, stream>>>(cosb, sinb);
    embed_kernel<<<ROWS, 256, 0, stream>>>(ids, ue, be, h, h0);

    auto gemm = [&](int mode, bool bf16out, const unsigned short* A, const unsigned short* B,
                    void* C, int M, int N, int K, int lda, int ldb, int ldc) {
        dim3 g(M / 128, N / 128);
        if (mode == 0 && !bf16out)
            gemm_bf16_kernel<0, false><<<g, 256, 0, stream>>>(A, B, C, M, N, K, lda, ldb, ldc);
        else if (mode == 0 && bf16out)
            gemm_bf16_kernel<0, true><<<g, 256, 0, stream>>>(A, B, C, M, N, K, lda, ldb, ldc);
        else if (mode == 1)
            gemm_bf16_kernel<1, true><<<g, 256, 0, stream>>>(A, B, C, M, N, K, lda, ldb, ldc);
        else
            gemm_bf16_kernel<2, false><<<g, 256, 0, stream>>>(A, B, C, M, N, K, lda, ldb, ldc);
    };

    auto run_block = [&](int l, float* dup) {
        // stage this layer's weights as bf16
        cvt(Wq + (size_t)l * Dm * Dm,       wqkvb,              (size_t)Dm * Dm);
        cvt(Wk + (size_t)l * 256 * Dm,      wqkvb + 1024 * Dm,  (size_t)256 * Dm);
        cvt(Wv + (size_t)l * 256 * Dm,      wqkvb + 1280 * Dm,  (size_t)256 * Dm);
        cvt(Wo + (size_t)l * Dm * Dm,       wob,                (size_t)Dm * Dm);
        cvt(Wf + (size_t)l * 3 * Dm * Dm,   wfb,                (size_t)3 * Dm * Dm);
        cvt(Wo2 + (size_t)l * 3 * Dm * Dm,  wo2b,               (size_t)3 * Dm * Dm);

        resmix_kernel<<<ROWS, 256, 0, stream>>>(h, h0, rm + (size_t)l * 2 * Dm, xnb);
        gemm(0, true, xnb, wqkvb, qkvb, ROWS, 1536, Dm, Dm, Dm, 1536);
        qknorm_rope_kernel<<<ROWS * NHn / 4, 256, 0, stream>>>(
            qkvb, 1536, 0, qbf, 1024, NHn, cosb, sinb, qg + (size_t)l * NHn, 0.125f);
        qknorm_rope_kernel<<<ROWS * NKVn / 4, 256, 0, stream>>>(
            qkvb, 1536, 1024, kbf, 256, NKVn, cosb, sinb, nullptr, 1.f);
        vtrans_kernel<<<dim3(ROWS / 32, 8), 256, 0, stream>>>(qkvb, 1536, 1280, vtb);
        attn_mfma_kernel<<<Bn * NHn * (Sn / 64), 256, 0, stream>>>(qbf, kbf, vtb, attb);
        gemm(0, false, attb, wob, proj, ROWS, Dm, Dm, Dm, Dm, Dm);
        axpy_kernel<true><<<ROWS, 256, 0, stream>>>(h, proj, asc + (size_t)l * Dm, xnb, nullptr);
        gemm(1, true, xnb, wfb, hidb, ROWS, 3 * Dm, Dm, Dm, Dm, 3 * Dm);
        gemm(0, false, hidb, wo2b, proj, ROWS, Dm, 3 * Dm, 3 * Dm, 3 * Dm, Dm);
        axpy_kernel<false><<<ROWS, 256, 0, stream>>>(h, proj, msc + (size_t)l * Dm, nullptr, dup);
    };

    for (int l = 0; l < Ln; ++l)
        run_block(l, skb + (size_t)l * ROWS * Dm);
    for (int i = 0; i < Ln; ++i) {
        int j = Ln - 1 - i;
        axpy_kernel<false><<<ROWS, 256, 0, stream>>>(h, skb + (size_t)j * ROWS * Dm,
                                                     sw + (size_t)i * Dm, nullptr, nullptr);
        run_block(j, nullptr);
    }

    // final norm + LM head (chunk aliases skb — skips no longer needed)
    rmsn_kernel<<<ROWS, 256, 0, stream>>>(h, xnb);
    loss_init_kernel<<<(ROWS + 255) / 256, 256, 0, stream>>>(mrow, srow, tgv);
    for (int c0 = 0; c0 < VSn; c0 += VCHUNK) {
        int Nc = (VSn - c0 < VCHUNK) ? (VSn - c0) : VCHUNK;
        int Ng = (VPAD - c0 < VCHUNK) ? (VPAD - c0) : VCHUNK;   // mult of 128
        gemm(2, false, xnb, ueb + (size_t)c0 * 512, chunk, ROWS, Ng, 512, Dm, 512, VCHUNK);
        chunk_reduce_kernel<<<ROWS, 256, 0, stream>>>(chunk, Nc, c0, yv, mrow, srow, tgv);
    }
    loss_final_kernel<<<1, 256, 0, stream>>>(mrow, srow, tgv, (float*)d_out);
}

// Round 4
// 4998.658 us; speedup vs baseline: 6.1768x; 1.0559x over previous
//
#include <hip/hip_runtime.h>
#include <cstdint>
#include <cstddef>

// ---------------- constants (from reference) ----------------
constexpr int   Dm    = 1024;
constexpr int   NHn   = 16;
constexpr int   NKVn  = 4;
constexpr int   HDn   = 64;
constexpr int   Ln    = 6;
constexpr int   Sn    = 2048;
constexpr int   Bn    = 2;
constexpr int   ROWS  = Bn * Sn;          // 4096 token rows
constexpr int   VSn   = 50257;
constexpr int   HSn   = 4096;
constexpr float EPSF  = 1.1920929e-07f;
constexpr int   VCHUNK = 4096;            // vocab chunk for LM head
constexpr int   VPAD   = 50304;           // 393*128
constexpr float LOG2E  = 1.44269504f;

#define DEV __device__ __forceinline__

typedef __attribute__((ext_vector_type(8))) short bf16x8;
typedef __attribute__((ext_vector_type(4))) float f32x4;
using ush = unsigned short;

DEV ush f2bf(float f) {
    unsigned int u = __float_as_uint(f);
    u = (u + 0x7fffu + ((u >> 16) & 1u)) >> 16;
    return (ush)u;
}

DEV float b2f(ush v) {
    return __uint_as_float(((unsigned int)v) << 16);
}

DEV f32x4 mfma16(bf16x8 a, bf16x8 b, f32x4 c) {
    return __builtin_amdgcn_mfma_f32_16x16x32_bf16(a, b, c, 0, 0, 0);
}

DEV void llds16(const ush* g, ush* l) {
    __builtin_amdgcn_global_load_lds(
        (const __attribute__((address_space(1))) void*)g,
        (__attribute__((address_space(3))) void*)l, 16, 0, 0);
}

// ---------------- block reductions (256 threads = 4 waves) ----------------
DEV float block_sum256(float v, float* red) {
#pragma unroll
    for (int off = 32; off; off >>= 1) v += __shfl_xor(v, off);
    __syncthreads();
    if ((threadIdx.x & 63) == 0) red[threadIdx.x >> 6] = v;
    __syncthreads();
    return red[0] + red[1] + red[2] + red[3];
}

DEV float block_max256(float v, float* red) {
#pragma unroll
    for (int off = 32; off; off >>= 1) v = fmaxf(v, __shfl_xor(v, off));
    __syncthreads();
    if ((threadIdx.x & 63) == 0) red[threadIdx.x >> 6] = v;
    __syncthreads();
    return fmaxf(fmaxf(red[0], red[1]), fmaxf(red[2], red[3]));
}

// ---------------- rope tables ----------------
__global__ void rope_kernel(float* __restrict__ cb, float* __restrict__ sb) {
    int idx = blockIdx.x * 256 + threadIdx.x;
    if (idx >= Sn * 32) return;
    int t = idx >> 5, f = idx & 31;
    float freq = powf(10000.f, -(float)f * (1.f / 32.f));
    float ang  = (float)t * freq;
    cb[idx] = cosf(ang);
    sb[idx] = sinf(ang);
}

// ---------------- fp32 -> bf16 convert / zero pad ----------------
__global__ void cvt_bf16_kernel(const float* __restrict__ s, ush* __restrict__ d, int n4) {
    int i = blockIdx.x * 256 + threadIdx.x;
    if (i >= n4) return;
    float4 v = *(const float4*)(s + (size_t)i * 4);
    ushort4 o;
    o.x = f2bf(v.x); o.y = f2bf(v.y); o.z = f2bf(v.z); o.w = f2bf(v.w);
    *(ushort4*)(d + (size_t)i * 4) = o;
}

__global__ void zpad_kernel(ush* __restrict__ p, int n) {
    int i = blockIdx.x * 256 + threadIdx.x;
    if (i < n) p[i] = 0;
}

// ---------------- embedding + rmsn ----------------
__global__ __launch_bounds__(256)
void embed_kernel(const int* __restrict__ ids, const float* __restrict__ ue,
                  const float* __restrict__ be, float* __restrict__ h,
                  float* __restrict__ h0) {
    __shared__ float red[4];
    int r = blockIdx.x;
    int s = r % Sn;
    int id = ids[r];
    int prev = (s == 0) ? 0 : ids[r - 1];
    int bi = ((prev % HSn) * (VSn % HSn) % HSn + id % HSn) % HSn;
    int tid = threadIdx.x;
    float vals[4];
    float ss = 0.f;
#pragma unroll
    for (int t = 0; t < 4; ++t) {
        int j = tid + t * 256;
        float v = (j < 512) ? ue[(size_t)id * 512 + j]
                            : be[(size_t)bi * 512 + (j - 512)];
        vals[t] = v; ss += v * v;
    }
    ss = block_sum256(ss, red);
    float rinv = rsqrtf(ss * (1.f / Dm) + EPSF);
#pragma unroll
    for (int t = 0; t < 4; ++t) {
        int j = tid + t * 256;
        float v = vals[t] * rinv;
        h [(size_t)r * Dm + j] = v;
        h0[(size_t)r * Dm + j] = v;
    }
}

// ---------------- residual mix + rmsn -> bf16 ----------------
__global__ __launch_bounds__(256)
void resmix_kernel(float* __restrict__ h, const float* __restrict__ h0,
                   const float* __restrict__ rm0, ush* __restrict__ xnb) {
    __shared__ float red[4];
    int r = blockIdx.x, tid = threadIdx.x;
    const float* rm1 = rm0 + Dm;
    float vals[4]; float ss = 0.f;
#pragma unroll
    for (int t = 0; t < 4; ++t) {
        int j = tid + t * 256;
        size_t o = (size_t)r * Dm + j;
        float v = rm0[j] * h[o] + rm1[j] * h0[o];
        vals[t] = v; ss += v * v;
        h[o] = v;
    }
    ss = block_sum256(ss, red);
    float rinv = rsqrtf(ss * (1.f / Dm) + EPSF);
#pragma unroll
    for (int t = 0; t < 4; ++t)
        xnb[(size_t)r * Dm + tid + t * 256] = f2bf(vals[t] * rinv);
}

// ---------------- standalone rmsn -> bf16 ----------------
__global__ __launch_bounds__(256)
void rmsn_kernel(const float* __restrict__ x, ush* __restrict__ out) {
    __shared__ float red[4];
    int r = blockIdx.x, tid = threadIdx.x;
    float vals[4]; float ss = 0.f;
#pragma unroll
    for (int t = 0; t < 4; ++t) {
        float v = x[(size_t)r * Dm + tid + t * 256];
        vals[t] = v; ss += v * v;
    }
    ss = block_sum256(ss, red);
    float rinv = rsqrtf(ss * (1.f / Dm) + EPSF);
#pragma unroll
    for (int t = 0; t < 4; ++t)
        out[(size_t)r * Dm + tid + t * 256] = f2bf(vals[t] * rinv);
}

// ---------------- reverse-pass skip add: h += sc * bf16(skb) ----------------
__global__ __launch_bounds__(256)
void skipadd_kernel(float* __restrict__ h, const ush* __restrict__ skb,
                    const float* __restrict__ sc) {
    int r = blockIdx.x, tid = threadIdx.x;
#pragma unroll
    for (int t = 0; t < 4; ++t) {
        int j = tid + t * 256;
        size_t o = (size_t)r * Dm + j;
        h[o] = fmaf(sc[j], b2f(skb[o]), h[o]);
    }
}

// ---------------- bf16 MFMA GEMM: C(MxN) = A(MxK) @ B(NxK)^T ----------------
// TM in {64,128}. MODE 0: bf16 store  1: relu^2 bf16  2: 30*tanh(v/30) bf16
// MODE 3: residual add  h[row*ldc+col] += sc[col]*acc  (+ optional bf16 dup)
template<int TM, int MODE>
__global__ __launch_bounds__(256)
void gemm_k(const ush* __restrict__ A, const ush* __restrict__ B,
            ush* __restrict__ C, int M, int N, int K,
            int lda, int ldb, int ldc,
            float* __restrict__ hres, const float* __restrict__ sc,
            ush* __restrict__ dup) {
    __shared__ __align__(16) ush As[TM * 32];
    __shared__ __align__(16) ush Bs[128 * 32];
    const int m0 = blockIdx.x * TM, n0 = blockIdx.y * 128;
    const int tid  = threadIdx.x;
    const int w    = tid >> 6, lane = tid & 63;
    const int l15  = lane & 15, quad = lane >> 4;
    const int wr   = w >> 1, wc = w & 1;
    constexpr int NI = TM / 32;        // acc row-tiles per wave (4 or 2)

    const int srow = lane >> 2, sch = lane & 3;
    const ush* Ag;
    ush* AsW;
    if constexpr (TM == 128) {
        Ag  = A + (size_t)(m0 + w * 32 + srow) * lda + sch * 8;
        AsW = As + w * 1024;
    } else {
        Ag  = A + (size_t)(m0 + w * 16 + srow) * lda + sch * 8;
        AsW = As + w * 512;
    }
    const ush* Bg = B + (size_t)(n0 + w * 32 + srow) * ldb + sch * 8;
    ush* BsW = Bs + w * 1024;

    f32x4 acc[NI][4] = {};

    for (int k0 = 0; k0 < K; k0 += 32) {
        __syncthreads();
        llds16(Ag + k0, AsW);
        if constexpr (TM == 128) llds16(Ag + k0 + 16 * lda, AsW + 512);
        llds16(Bg + k0,            BsW);
        llds16(Bg + k0 + 16 * ldb, BsW + 512);
        __syncthreads();
        bf16x8 af[NI], bfv[4];
#pragma unroll
        for (int i = 0; i < NI; ++i)
            af[i] = *(const bf16x8*)&As[(wr * (TM / 2) + i * 16 + l15) * 32 + quad * 8];
#pragma unroll
        for (int j = 0; j < 4; ++j)
            bfv[j] = *(const bf16x8*)&Bs[(wc * 64 + j * 16 + l15) * 32 + quad * 8];
#pragma unroll
        for (int i = 0; i < NI; ++i)
#pragma unroll
            for (int j = 0; j < 4; ++j)
                acc[i][j] = mfma16(af[i], bfv[j], acc[i][j]);
    }

#pragma unroll
    for (int i = 0; i < NI; ++i) {
#pragma unroll
        for (int j = 0; j < 4; ++j) {
            int row = m0 + wr * (TM / 2) + i * 16 + quad * 4;
            int col = n0 + wc * 64 + j * 16 + l15;
#pragma unroll
            for (int r = 0; r < 4; ++r) {
                float v = acc[i][j][r];
                if (MODE == 1) { v = fmaxf(v, 0.f); v = v * v; }
                else if (MODE == 2) {
                    float ax = fabsf(v) * (1.f / 30.f);
                    float e  = __expf(-2.f * ax);
                    float t  = (1.f - e) / (1.f + e);
                    v = copysignf(t * 30.f, v);
                }
                if (MODE == 3) {
                    size_t o = (size_t)(row + r) * ldc + col;
                    float nv = fmaf(sc[col], v, hres[o]);
                    hres[o] = nv;
                    if (dup) dup[o] = f2bf(nv);
                } else {
                    C[(size_t)(row + r) * ldc + col] = f2bf(v);
                }
            }
        }
    }
}

// ---------------- per-head rmsn + rope -> bf16 (bf16 input) ----------------
__global__ __launch_bounds__(256)
void qknorm_rope_kernel(const ush* __restrict__ in, int in_ld, int in_off,
                        ush* __restrict__ out, int out_ld, int heads,
                        const float* __restrict__ cosb, const float* __restrict__ sinb,
                        const float* __restrict__ qg, float scale) {
    int row  = blockIdx.x * 4 + (threadIdx.x >> 6);   // token*heads + hh
    int lane = threadIdx.x & 63;
    int hh   = row % heads;
    int t    = row / heads;
    int sidx = t % Sn;
    float x = b2f(in[(size_t)t * in_ld + in_off + hh * 64 + lane]);
    float ss = x * x;
#pragma unroll
    for (int off = 32; off; off >>= 1) ss += __shfl_xor(ss, off);
    float xn = x * rsqrtf(ss * (1.f / HDn) + EPSF);
    float partner = __shfl_xor(xn, 32);
    int f = lane & 31;
    float c  = cosb[sidx * 32 + f];
    float sv = sinb[sidx * 32 + f];
    float o = (lane < 32) ? fmaf(xn, c, partner * sv)
                          : fmaf(xn, c, -partner * sv);
    if (qg) o *= qg[hh] * scale;
    out[(size_t)t * out_ld + hh * 64 + lane] = f2bf(o);
}

// ---------------- V transpose: bf16 [4096][in_ld] (cols off..off+255) -> bf16 [256][4096] ----------------
__global__ __launch_bounds__(256)
void vtrans_kernel(const ush* __restrict__ in, int in_ld, int in_off,
                   ush* __restrict__ out) {
    __shared__ ush tile[32][33];
    int s0 = blockIdx.x * 32;
    int c0 = blockIdx.y * 32;
    int i = threadIdx.x >> 5;
    int j = threadIdx.x & 31;
#pragma unroll
    for (int k = 0; k < 4; ++k)
        tile[i + k * 8][j] = in[(size_t)(s0 + i + k * 8) * in_ld + in_off + c0 + j];
    __syncthreads();
#pragma unroll
    for (int k = 0; k < 4; ++k)
        out[(size_t)(c0 + i + k * 8) * (size_t)ROWS + s0 + j] = tile[j][i + k * 8];
}

// ---------------- causal GQA flash attention, bf16 MFMA, static-max softmax ----------------
// qb: bf16 [token][1024] (qg * 0.125 * log2e folded), kb: bf16 [token][256],
// vt: bf16 [256][4096] (transposed), ob: bf16 [token][1024].
// Scores are bounded: |s'| <= 8*|qg[h]|*log2e, so use fixed max -> no per-iter
// reductions or rescaling; l reduced once at the end.
__global__ __launch_bounds__(256)
void attn_mfma_kernel(const ush* __restrict__ qb,
                      const ush* __restrict__ kb,
                      const ush* __restrict__ vt,
                      ush* __restrict__ ob,
                      const float* __restrict__ qgl) {
    __shared__ __align__(16) ush Ks[64 * 72];
    __shared__ __align__(16) ush Vs[64 * 72];
    __shared__ __align__(16) ush Ps[64 * 72];
    const int tile = blockIdx.x & 31;
    const int h    = (blockIdx.x >> 5) & 15;
    const int b    = blockIdx.x >> 9;
    const int kvh  = h >> 2;
    const int w    = threadIdx.x >> 6, lane = threadIdx.x & 63;
    const int l15  = lane & 15, quad = lane >> 4;
    const int q0   = tile * 64;
    const float mfix = 8.f * fabsf(qgl[h]) * LOG2E;

    const size_t qrow = (size_t)(b * Sn + q0 + w * 16 + l15) * 1024 + h * 64;
    bf16x8 qf0 = *(const bf16x8*)(qb + qrow + quad * 8);
    bf16x8 qf1 = *(const bf16x8*)(qb + qrow + 32 + quad * 8);

    f32x4 Oacc[4] = {};
    float lsum[4] = {0.f, 0.f, 0.f, 0.f};
    const int qbase = q0 + w * 16 + quad * 4;   // + r

    const int nblk = tile + 1;
    for (int kb_i = 0; kb_i < nblk; ++kb_i) {
        const int k0 = kb_i * 64;
        __syncthreads();
        {
            const size_t kgb = (size_t)(b * Sn + k0) * 256 + kvh * 64;
            const size_t vgb = (size_t)(kvh * 64) * (size_t)ROWS + b * Sn + k0;
#pragma unroll
            for (int ii = 0; ii < 2; ++ii) {
                int idx = threadIdx.x + ii * 256;
                int rr = idx >> 3, ch = idx & 7;
                uint4 kvl = *(const uint4*)(kb + kgb + (size_t)rr * 256 + ch * 8);
                *(uint4*)&Ks[rr * 72 + ch * 8] = kvl;
                uint4 vvl = *(const uint4*)(vt + vgb + (size_t)rr * (size_t)ROWS + ch * 8);
                *(uint4*)&Vs[rr * 72 + ch * 8] = vvl;
            }
        }
        __syncthreads();

        // QK^T
        f32x4 S[4] = {};
#pragma unroll
        for (int c = 0; c < 4; ++c) {
            bf16x8 kf0 = *(const bf16x8*)&Ks[(c * 16 + l15) * 72 + quad * 8];
            bf16x8 kf1 = *(const bf16x8*)&Ks[(c * 16 + l15) * 72 + 32 + quad * 8];
            S[c] = mfma16(qf0, kf0, S[c]);
            S[c] = mfma16(qf1, kf1, S[c]);
        }

        // mask only the diagonal block; p = exp2(s' - mfix)
        if (kb_i == tile) {
#pragma unroll
            for (int c = 0; c < 4; ++c) {
                int key = k0 + c * 16 + l15;
#pragma unroll
                for (int r = 0; r < 4; ++r)
                    if (key > qbase + r) S[c][r] = -INFINITY;
            }
        }
#pragma unroll
        for (int c = 0; c < 4; ++c)
#pragma unroll
            for (int r = 0; r < 4; ++r) {
                float p = exp2f(S[c][r] - mfix);
                S[c][r] = p;
                lsum[r] += p;
            }

        // P -> LDS (wave-private region), A-operand layout [q][key]
#pragma unroll
        for (int c = 0; c < 4; ++c)
#pragma unroll
            for (int r = 0; r < 4; ++r)
                Ps[(w * 16 + quad * 4 + r) * 72 + c * 16 + l15] = f2bf(S[c][r]);

        // PV
        bf16x8 pf0 = *(const bf16x8*)&Ps[(w * 16 + l15) * 72 + quad * 8];
        bf16x8 pf1 = *(const bf16x8*)&Ps[(w * 16 + l15) * 72 + 32 + quad * 8];
#pragma unroll
        for (int dt = 0; dt < 4; ++dt) {
            bf16x8 vf0 = *(const bf16x8*)&Vs[(dt * 16 + l15) * 72 + quad * 8];
            bf16x8 vf1 = *(const bf16x8*)&Vs[(dt * 16 + l15) * 72 + 32 + quad * 8];
            Oacc[dt] = mfma16(pf0, vf0, Oacc[dt]);
            Oacc[dt] = mfma16(pf1, vf1, Oacc[dt]);
        }
    }

    // one deferred l-reduction across the 16 lanes of each quad-row group
#pragma unroll
    for (int m = 1; m <= 8; m <<= 1)
#pragma unroll
        for (int r = 0; r < 4; ++r)
            lsum[r] += __shfl_xor(lsum[r], m);

#pragma unroll
    for (int dt = 0; dt < 4; ++dt)
#pragma unroll
        for (int r = 0; r < 4; ++r) {
            size_t o = (size_t)(b * Sn + qbase + r) * 1024 + h * 64 + dt * 16 + l15;
            ob[o] = f2bf(Oacc[dt][r] / fmaxf(lsum[r], 1e-35f));
        }
}

// ---------------- LM head loss reductions (bf16 chunk) ----------------
__global__ void loss_init_kernel(float* __restrict__ m, float* __restrict__ s,
                                 float* __restrict__ tg) {
    int i = blockIdx.x * 256 + threadIdx.x;
    if (i < ROWS) { m[i] = -INFINITY; s[i] = 0.f; tg[i] = 0.f; }
}

__global__ __launch_bounds__(256)
void chunk_reduce_kernel(const ush* __restrict__ Cc, int Nc, int c0,
                         const int* __restrict__ y, float* __restrict__ m,
                         float* __restrict__ s, float* __restrict__ tg) {
    __shared__ float red[4];
    int r = blockIdx.x, tid = threadIdx.x;
    const ush* row = Cc + (size_t)r * VCHUNK;
    float v[16];
    float mx = -INFINITY;
#pragma unroll
    for (int t = 0; t < 16; ++t) {
        int j = tid + t * 256;
        v[t] = (j < Nc) ? b2f(row[j]) : -INFINITY;
        mx = fmaxf(mx, v[t]);
    }
    mx = block_max256(mx, red);
    float se = 0.f;
#pragma unroll
    for (int t = 0; t < 16; ++t)
        se += __expf(v[t] - mx);      // exp(-inf)=0 for padding
    se = block_sum256(se, red);
    if (tid == 0) {
        float mo = m[r];
        float mn = fmaxf(mo, mx);
        s[r] = s[r] * __expf(mo - mn) + se * __expf(mx - mn);
        m[r] = mn;
        int t = y[r] - c0;
        if (t >= 0 && t < Nc) tg[r] = b2f(row[t]);
    }
}

__global__ __launch_bounds__(256)
void loss_final_kernel(const float* __restrict__ m, const float* __restrict__ s,
                       const float* __restrict__ tg, float* __restrict__ out) {
    __shared__ float red[4];
    float part = 0.f;
    for (int r = threadIdx.x; r < ROWS; r += 256)
        part += m[r] + logf(s[r]) - tg[r];
    part = block_sum256(part, red);
    if (threadIdx.x == 0) out[0] = part * (1.f / ROWS);
}

// ---------------- host orchestration ----------------
extern "C" void kernel_launch(void* const* d_in, const int* in_sizes, int n_in,
                              void* d_out, int out_size, void* d_ws, size_t ws_size,
                              hipStream_t stream) {
    const int*   ids = (const int*)d_in[0];
    const int*   yv  = (const int*)d_in[1];
    const float* ue  = (const float*)d_in[2];
    const float* be  = (const float*)d_in[3];
    const float* Wq  = (const float*)d_in[4];
    const float* Wk  = (const float*)d_in[5];
    const float* Wv  = (const float*)d_in[6];
    const float* Wo  = (const float*)d_in[7];
    const float* qg  = (const float*)d_in[8];
    const float* asc = (const float*)d_in[9];
    const float* msc = (const float*)d_in[10];
    const float* rm  = (const float*)d_in[11];
    const float* Wf  = (const float*)d_in[12];
    const float* Wo2 = (const float*)d_in[13];
    const float* sw  = (const float*)d_in[14];
    (void)in_sizes; (void)n_in; (void)out_size; (void)ws_size;

    char* wsb = (char*)d_ws;
    size_t off = 0;
    auto alloc = [&](size_t bytes) {
        void* p = (void*)(wsb + off);
        off += ((bytes + 255) & ~size_t(255));
        return p;
    };
    // fp32 (~214 MB total; known-good <= 278 MB)
    float* h    = (float*)alloc((size_t)ROWS * Dm * 4);                // 16 MB
    float* h0   = (float*)alloc((size_t)ROWS * Dm * 4);                // 16 MB
    float* cosb = (float*)alloc((size_t)Sn * 32 * 4);
    float* sinb = (float*)alloc((size_t)Sn * 32 * 4);
    float* mrow = (float*)alloc(ROWS * 4);
    float* srow = (float*)alloc(ROWS * 4);
    float* tgv  = (float*)alloc(ROWS * 4);
    // bf16
    ush* skb  = (ush*)alloc((size_t)Ln * ROWS * Dm * 2);   // 48 MB (bf16 skips)
    ush* xnb  = (ush*)alloc((size_t)ROWS * Dm * 2);        // 8 MB
    ush* qkvb = (ush*)alloc((size_t)ROWS * 1536 * 2);      // 12 MB
    ush* qbf  = (ush*)alloc((size_t)ROWS * Dm * 2);        // 8 MB
    ush* kbf  = (ush*)alloc((size_t)ROWS * 256 * 2);       // 2 MB
    ush* vtb  = (ush*)alloc((size_t)256 * ROWS * 2);       // 2 MB
    ush* attb = (ush*)alloc((size_t)ROWS * Dm * 2);        // 8 MB
    ush* hidb = (ush*)alloc((size_t)ROWS * 3 * Dm * 2);    // 24 MB
    ush* wbuf = (ush*)alloc((size_t)8704 * 1024 * 2);      // 17.8 MB per-layer weights
    ush* ueb  = (ush*)alloc((size_t)VPAD * 512 * 2);       // 51.5 MB
    // bf16 LM-head chunk (32 MB) aliases skb (skips dead by then)
    ush* chunk = skb;

    ush* wqkvb = wbuf;                          // 1536*1024
    ush* wob   = wbuf + (size_t)1536 * 1024;    // 1024*1024
    ush* wfb   = wbuf + (size_t)2560 * 1024;    // 3072*1024
    ush* wo2b  = wbuf + (size_t)5632 * 1024;    // 3072*1024

    auto cvt = [&](const float* s, ush* d, size_t n) {
        int n4 = (int)(n / 4);
        cvt_bf16_kernel<<<(n4 + 255) / 256, 256, 0, stream>>>(s, d, n4);
    };

    cvt(ue, ueb, (size_t)VSn * 512);
    zpad_kernel<<<((VPAD - VSn) * 512 + 255) / 256, 256, 0, stream>>>(
        ueb + (size_t)VSn * 512, (VPAD - VSn) * 512);

    rope_kernel<<<(Sn * 32 + 255) / 256, 256, 0, stream>>>(cosb, sinb);
    embed_kernel<<<ROWS, 256, 0, stream>>>(ids, ue, be, h, h0);

    auto run_block = [&](int l, ush* dup) {
        cvt(Wq + (size_t)l * Dm * Dm,       wqkvb,              (size_t)Dm * Dm);
        cvt(Wk + (size_t)l * 256 * Dm,      wqkvb + 1024 * Dm,  (size_t)256 * Dm);
        cvt(Wv + (size_t)l * 256 * Dm,      wqkvb + 1280 * Dm,  (size_t)256 * Dm);
        cvt(Wo + (size_t)l * Dm * Dm,       wob,                (size_t)Dm * Dm);
        cvt(Wf + (size_t)l * 3 * Dm * Dm,   wfb,                (size_t)3 * Dm * Dm);
        cvt(Wo2 + (size_t)l * 3 * Dm * Dm,  wo2b,               (size_t)3 * Dm * Dm);

        resmix_kernel<<<ROWS, 256, 0, stream>>>(h, h0, rm + (size_t)l * 2 * Dm, xnb);
        // QKV: 64x128 tiles -> 64*12=768 blocks (3/CU)
        gemm_k<64, 0><<<dim3(ROWS / 64, 1536 / 128), 256, 0, stream>>>(
            xnb, wqkvb, qkvb, ROWS, 1536, Dm, Dm, Dm, 1536, nullptr, nullptr, nullptr);
        qknorm_rope_kernel<<<ROWS * NHn / 4, 256, 0, stream>>>(
            qkvb, 1536, 0, qbf, 1024, NHn, cosb, sinb,
            qg + (size_t)l * NHn, 0.125f * LOG2E);
        qknorm_rope_kernel<<<ROWS * NKVn / 4, 256, 0, stream>>>(
            qkvb, 1536, 1024, kbf, 256, NKVn, cosb, sinb, nullptr, 1.f);
        vtrans_kernel<<<dim3(ROWS / 32, 8), 256, 0, stream>>>(qkvb, 1536, 1280, vtb);
        attn_mfma_kernel<<<Bn * NHn * (Sn / 64), 256, 0, stream>>>(
            qbf, kbf, vtb, attb, qg + (size_t)l * NHn);
        // Wo with fused residual add: h += asc*acc
        gemm_k<64, 3><<<dim3(ROWS / 64, Dm / 128), 256, 0, stream>>>(
            attb, wob, nullptr, ROWS, Dm, Dm, Dm, Dm, Dm,
            h, asc + (size_t)l * Dm, nullptr);
        rmsn_kernel<<<ROWS, 256, 0, stream>>>(h, xnb);
        gemm_k<128, 1><<<dim3(ROWS / 128, 3 * Dm / 128), 256, 0, stream>>>(
            xnb, wfb, hidb, ROWS, 3 * Dm, Dm, Dm, Dm, 3 * Dm, nullptr, nullptr, nullptr);
        // Wo2 with fused residual add + bf16 skip dup
        gemm_k<64, 3><<<dim3(ROWS / 64, Dm / 128), 256, 0, stream>>>(
            hidb, wo2b, nullptr, ROWS, Dm, 3 * Dm, 3 * Dm, 3 * Dm, Dm,
            h, msc + (size_t)l * Dm, dup);
    };

    for (int l = 0; l < Ln; ++l)
        run_block(l, skb + (size_t)l * ROWS * Dm);
    for (int i = 0; i < Ln; ++i) {
        int j = Ln - 1 - i;
        skipadd_kernel<<<ROWS, 256, 0, stream>>>(h, skb + (size_t)j * ROWS * Dm,
                                                 sw + (size_t)i * Dm);
        run_block(j, nullptr);
    }

    // final norm + LM head (bf16 chunk aliases skb)
    rmsn_kernel<<<ROWS, 256, 0, stream>>>(h, xnb);
    loss_init_kernel<<<(ROWS + 255) / 256, 256, 0, stream>>>(mrow, srow, tgv);
    for (int c0 = 0; c0 < VSn; c0 += VCHUNK) {
        int Nc = (VSn - c0 < VCHUNK) ? (VSn - c0) : VCHUNK;
        int Ng = (VPAD - c0 < VCHUNK) ? (VPAD - c0) : VCHUNK;   // mult of 128
        gemm_k<128, 2><<<dim3(ROWS / 128, Ng / 128), 256, 0, stream>>>(
            xnb, ueb + (size_t)c0 * 512, chunk, ROWS, Ng, 512, Dm, 512, VCHUNK,
            nullptr, nullptr, nullptr);
        chunk_reduce_kernel<<<ROWS, 256, 0, stream>>>(chunk, Nc, c0, yv, mrow, srow, tgv);
    }
    loss_final_kernel<<<1, 256, 0, stream>>>(mrow, srow, tgv, (float*)d_out);
}

// Round 5
// 4389.961 us; speedup vs baseline: 7.0332x; 1.1387x over previous
//
#include <hip/hip_runtime.h>
#include <cstdint>
#include <cstddef>

// ---------------- constants (from reference) ----------------
constexpr int   Dm    = 1024;
constexpr int   NHn   = 16;
constexpr int   NKVn  = 4;
constexpr int   HDn   = 64;
constexpr int   Ln    = 6;
constexpr int   Sn    = 2048;
constexpr int   Bn    = 2;
constexpr int   ROWS  = Bn * Sn;          // 4096 token rows
constexpr int   VSn   = 50257;
constexpr int   HSn   = 4096;
constexpr float EPSF  = 1.1920929e-07f;
constexpr int   VCHUNK = 4096;            // vocab chunk for LM head
constexpr int   VPAD   = 50304;           // 393*128
constexpr float LOG2E  = 1.44269504f;

#define DEV __device__ __forceinline__

typedef __attribute__((ext_vector_type(8))) short bf16x8;
typedef __attribute__((ext_vector_type(4))) float f32x4;
using ush = unsigned short;

DEV ush f2bf(float f) {
    unsigned int u = __float_as_uint(f);
    u = (u + 0x7fffu + ((u >> 16) & 1u)) >> 16;
    return (ush)u;
}

DEV float b2f(ush v) {
    return __uint_as_float(((unsigned int)v) << 16);
}

DEV f32x4 mfma16(bf16x8 a, bf16x8 b, f32x4 c) {
    return __builtin_amdgcn_mfma_f32_16x16x32_bf16(a, b, c, 0, 0, 0);
}

DEV void llds16(const ush* g, ush* l) {
    __builtin_amdgcn_global_load_lds(
        (const __attribute__((address_space(1))) void*)g,
        (__attribute__((address_space(3))) void*)l, 16, 0, 0);
}

// ---------------- block reductions (256 threads = 4 waves) ----------------
DEV float block_sum256(float v, float* red) {
#pragma unroll
    for (int off = 32; off; off >>= 1) v += __shfl_xor(v, off);
    __syncthreads();
    if ((threadIdx.x & 63) == 0) red[threadIdx.x >> 6] = v;
    __syncthreads();
    return red[0] + red[1] + red[2] + red[3];
}

DEV float block_max256(float v, float* red) {
#pragma unroll
    for (int off = 32; off; off >>= 1) v = fmaxf(v, __shfl_xor(v, off));
    __syncthreads();
    if ((threadIdx.x & 63) == 0) red[threadIdx.x >> 6] = v;
    __syncthreads();
    return fmaxf(fmaxf(red[0], red[1]), fmaxf(red[2], red[3]));
}

// ---------------- rope tables ----------------
__global__ void rope_kernel(float* __restrict__ cb, float* __restrict__ sb) {
    int idx = blockIdx.x * 256 + threadIdx.x;
    if (idx >= Sn * 32) return;
    int t = idx >> 5, f = idx & 31;
    float freq = powf(10000.f, -(float)f * (1.f / 32.f));
    float ang  = (float)t * freq;
    cb[idx] = cosf(ang);
    sb[idx] = sinf(ang);
}

// ---------------- fp32 -> bf16 convert / zero pad ----------------
__global__ void cvt_bf16_kernel(const float* __restrict__ s, ush* __restrict__ d, int n4) {
    int i = blockIdx.x * 256 + threadIdx.x;
    if (i >= n4) return;
    float4 v = *(const float4*)(s + (size_t)i * 4);
    ushort4 o;
    o.x = f2bf(v.x); o.y = f2bf(v.y); o.z = f2bf(v.z); o.w = f2bf(v.w);
    *(ushort4*)(d + (size_t)i * 4) = o;
}

__global__ void zpad_kernel(ush* __restrict__ p, int n) {
    int i = blockIdx.x * 256 + threadIdx.x;
    if (i < n) p[i] = 0;
}

// ---------------- embedding + rmsn ----------------
__global__ __launch_bounds__(256)
void embed_kernel(const int* __restrict__ ids, const float* __restrict__ ue,
                  const float* __restrict__ be, float* __restrict__ h,
                  float* __restrict__ h0) {
    __shared__ float red[4];
    int r = blockIdx.x;
    int s = r % Sn;
    int id = ids[r];
    int prev = (s == 0) ? 0 : ids[r - 1];
    int bi = ((prev % HSn) * (VSn % HSn) % HSn + id % HSn) % HSn;
    int tid = threadIdx.x;
    float vals[4];
    float ss = 0.f;
#pragma unroll
    for (int t = 0; t < 4; ++t) {
        int j = tid + t * 256;
        float v = (j < 512) ? ue[(size_t)id * 512 + j]
                            : be[(size_t)bi * 512 + (j - 512)];
        vals[t] = v; ss += v * v;
    }
    ss = block_sum256(ss, red);
    float rinv = rsqrtf(ss * (1.f / Dm) + EPSF);
#pragma unroll
    for (int t = 0; t < 4; ++t) {
        int j = tid + t * 256;
        float v = vals[t] * rinv;
        h [(size_t)r * Dm + j] = v;
        h0[(size_t)r * Dm + j] = v;
    }
}

// ---------------- residual mix + rmsn -> bf16 ----------------
__global__ __launch_bounds__(256)
void resmix_kernel(float* __restrict__ h, const float* __restrict__ h0,
                   const float* __restrict__ rm0, ush* __restrict__ xnb) {
    __shared__ float red[4];
    int r = blockIdx.x, tid = threadIdx.x;
    const float* rm1 = rm0 + Dm;
    float vals[4]; float ss = 0.f;
#pragma unroll
    for (int t = 0; t < 4; ++t) {
        int j = tid + t * 256;
        size_t o = (size_t)r * Dm + j;
        float v = rm0[j] * h[o] + rm1[j] * h0[o];
        vals[t] = v; ss += v * v;
        h[o] = v;
    }
    ss = block_sum256(ss, red);
    float rinv = rsqrtf(ss * (1.f / Dm) + EPSF);
#pragma unroll
    for (int t = 0; t < 4; ++t)
        xnb[(size_t)r * Dm + tid + t * 256] = f2bf(vals[t] * rinv);
}

// ---------------- standalone rmsn -> bf16 ----------------
__global__ __launch_bounds__(256)
void rmsn_kernel(const float* __restrict__ x, ush* __restrict__ out) {
    __shared__ float red[4];
    int r = blockIdx.x, tid = threadIdx.x;
    float vals[4]; float ss = 0.f;
#pragma unroll
    for (int t = 0; t < 4; ++t) {
        float v = x[(size_t)r * Dm + tid + t * 256];
        vals[t] = v; ss += v * v;
    }
    ss = block_sum256(ss, red);
    float rinv = rsqrtf(ss * (1.f / Dm) + EPSF);
#pragma unroll
    for (int t = 0; t < 4; ++t)
        out[(size_t)r * Dm + tid + t * 256] = f2bf(vals[t] * rinv);
}

// ---------------- reverse-pass skip add: h += sc * bf16(skb) ----------------
__global__ __launch_bounds__(256)
void skipadd_kernel(float* __restrict__ h, const ush* __restrict__ skb,
                    const float* __restrict__ sc) {
    int r = blockIdx.x, tid = threadIdx.x;
#pragma unroll
    for (int t = 0; t < 4; ++t) {
        int j = tid + t * 256;
        size_t o = (size_t)r * Dm + j;
        h[o] = fmaf(sc[j], b2f(skb[o]), h[o]);
    }
}

// ---------------- bf16 MFMA GEMM: C(MxN) = A(MxK) @ B(NxK)^T ----------------
// TM in {64,128}. MODE 0: bf16 store  1: relu^2 bf16  2: 30*tanh(v/30) bf16
// MODE 3: residual add  h[row*ldc+col] += sc[col]*acc  (+ optional bf16 dup)
template<int TM, int MODE>
__global__ __launch_bounds__(256)
void gemm_k(const ush* __restrict__ A, const ush* __restrict__ B,
            ush* __restrict__ C, int M, int N, int K,
            int lda, int ldb, int ldc,
            float* __restrict__ hres, const float* __restrict__ sc,
            ush* __restrict__ dup) {
    __shared__ __align__(16) ush As[TM * 32];
    __shared__ __align__(16) ush Bs[128 * 32];
    const int m0 = blockIdx.x * TM, n0 = blockIdx.y * 128;
    const int tid  = threadIdx.x;
    const int w    = tid >> 6, lane = tid & 63;
    const int l15  = lane & 15, quad = lane >> 4;
    const int wr   = w >> 1, wc = w & 1;
    constexpr int NI = TM / 32;        // acc row-tiles per wave (4 or 2)

    const int srow = lane >> 2, sch = lane & 3;
    const ush* Ag;
    ush* AsW;
    if constexpr (TM == 128) {
        Ag  = A + (size_t)(m0 + w * 32 + srow) * lda + sch * 8;
        AsW = As + w * 1024;
    } else {
        Ag  = A + (size_t)(m0 + w * 16 + srow) * lda + sch * 8;
        AsW = As + w * 512;
    }
    const ush* Bg = B + (size_t)(n0 + w * 32 + srow) * ldb + sch * 8;
    ush* BsW = Bs + w * 1024;

    f32x4 acc[NI][4] = {};

    for (int k0 = 0; k0 < K; k0 += 32) {
        __syncthreads();
        llds16(Ag + k0, AsW);
        if constexpr (TM == 128) llds16(Ag + k0 + 16 * lda, AsW + 512);
        llds16(Bg + k0,            BsW);
        llds16(Bg + k0 + 16 * ldb, BsW + 512);
        __syncthreads();
        bf16x8 af[NI], bfv[4];
#pragma unroll
        for (int i = 0; i < NI; ++i)
            af[i] = *(const bf16x8*)&As[(wr * (TM / 2) + i * 16 + l15) * 32 + quad * 8];
#pragma unroll
        for (int j = 0; j < 4; ++j)
            bfv[j] = *(const bf16x8*)&Bs[(wc * 64 + j * 16 + l15) * 32 + quad * 8];
#pragma unroll
        for (int i = 0; i < NI; ++i)
#pragma unroll
            for (int j = 0; j < 4; ++j)
                acc[i][j] = mfma16(af[i], bfv[j], acc[i][j]);
    }

#pragma unroll
    for (int i = 0; i < NI; ++i) {
#pragma unroll
        for (int j = 0; j < 4; ++j) {
            int row = m0 + wr * (TM / 2) + i * 16 + quad * 4;
            int col = n0 + wc * 64 + j * 16 + l15;
#pragma unroll
            for (int r = 0; r < 4; ++r) {
                float v = acc[i][j][r];
                if (MODE == 1) { v = fmaxf(v, 0.f); v = v * v; }
                else if (MODE == 2) {
                    float ax = fabsf(v) * (1.f / 30.f);
                    float e  = __expf(-2.f * ax);
                    float t  = (1.f - e) / (1.f + e);
                    v = copysignf(t * 30.f, v);
                }
                if (MODE == 3) {
                    size_t o = (size_t)(row + r) * ldc + col;
                    float nv = fmaf(sc[col], v, hres[o]);
                    hres[o] = nv;
                    if (dup) dup[o] = f2bf(nv);
                } else {
                    C[(size_t)(row + r) * ldc + col] = f2bf(v);
                }
            }
        }
    }
}

// ---------------- fused q+k per-head rmsn + rope -> bf16 ----------------
// in: qkv bf16 [token][1536].  q heads (16) -> qbf [token][1024] with
// qg*0.125*log2e folded; k heads (4) at offset 1024 -> kbf [token][256].
__global__ __launch_bounds__(256)
void qknorm_rope_kernel(const ush* __restrict__ in,
                        ush* __restrict__ qout, ush* __restrict__ kout,
                        const float* __restrict__ cosb, const float* __restrict__ sinb,
                        const float* __restrict__ qg) {
    int idx  = blockIdx.x * 4 + (threadIdx.x >> 6);
    int lane = threadIdx.x & 63;
    int t, hh, in_off;
    ush* outp; int out_ld;
    bool isq = idx < ROWS * NHn;
    if (isq) { t = idx >> 4; hh = idx & 15; in_off = hh * 64; outp = qout; out_ld = 1024; }
    else { int i2 = idx - ROWS * NHn; t = i2 >> 2; hh = i2 & 3; in_off = 1024 + hh * 64; outp = kout; out_ld = 256; }
    int sidx = t % Sn;
    float x = b2f(in[(size_t)t * 1536 + in_off + lane]);
    float ss = x * x;
#pragma unroll
    for (int off = 32; off; off >>= 1) ss += __shfl_xor(ss, off);
    float xn = x * rsqrtf(ss * (1.f / HDn) + EPSF);
    float partner = __shfl_xor(xn, 32);
    int f = lane & 31;
    float c  = cosb[sidx * 32 + f];
    float sv = sinb[sidx * 32 + f];
    float o = (lane < 32) ? fmaf(xn, c, partner * sv)
                          : fmaf(xn, c, -partner * sv);
    if (isq) o *= qg[hh] * (0.125f * LOG2E);
    outp[(size_t)t * out_ld + hh * 64 + lane] = f2bf(o);
}

// ---------------- V transpose: bf16 [4096][1536] (cols 1280..1535) -> bf16 [256][4096] ----------------
__global__ __launch_bounds__(256)
void vtrans_kernel(const ush* __restrict__ in, ush* __restrict__ out) {
    __shared__ ush tile[32][33];
    int s0 = blockIdx.x * 32;
    int c0 = blockIdx.y * 32;
    int i = threadIdx.x >> 5;
    int j = threadIdx.x & 31;
#pragma unroll
    for (int k = 0; k < 4; ++k)
        tile[i + k * 8][j] = in[(size_t)(s0 + i + k * 8) * 1536 + 1280 + c0 + j];
    __syncthreads();
#pragma unroll
    for (int k = 0; k < 4; ++k)
        out[(size_t)(c0 + i + k * 8) * (size_t)ROWS + s0 + j] = tile[j][i + k * 8];
}

// ---------------- causal GQA flash attention, bf16 MFMA, static-max softmax ----------------
// 128 q rows per workgroup (wave w: rows w*32..w*32+31 as two 16-row frags).
// Register-prefetch double buffering of the 64-key K/V tiles; P packed into
// dwords (k, k+32) via truncating v_perm. Heavy tiles scheduled first.
__global__ __launch_bounds__(256)
void attn_mfma_kernel(const ush* __restrict__ qb,
                      const ush* __restrict__ kb,
                      const ush* __restrict__ vt,
                      ush* __restrict__ ob,
                      const float* __restrict__ qgl) {
    __shared__ __align__(16) ush Ks[64 * 72];
    __shared__ __align__(16) ush Vs[64 * 72];
    __shared__ __align__(16) unsigned int PsD[128 * 36];
    const int tile = 15 - (blockIdx.x & 15);        // heavy-first
    const int h    = (blockIdx.x >> 4) & 15;
    const int b    = blockIdx.x >> 8;
    const int kvh  = h >> 2;
    const int w    = threadIdx.x >> 6, lane = threadIdx.x & 63;
    const int l15  = lane & 15, quad = lane >> 4;
    const int q0   = tile * 128;
    const float mfix = 8.f * fabsf(qgl[h]) * LOG2E;

    // Q fragments: wave w covers q rows q0+w*32 .. +31 (frags f=0,1)
    bf16x8 qf[2][2];
    {
        size_t qr = (size_t)(b * Sn + q0 + w * 32 + l15) * 1024 + h * 64;
        qf[0][0] = *(const bf16x8*)(qb + qr + quad * 8);
        qf[0][1] = *(const bf16x8*)(qb + qr + 32 + quad * 8);
        qf[1][0] = *(const bf16x8*)(qb + qr + 16 * 1024 + quad * 8);
        qf[1][1] = *(const bf16x8*)(qb + qr + 16 * 1024 + 32 + quad * 8);
    }
    f32x4 Oacc[2][4] = {};
    float lsum[2][4] = {{0.f,0.f,0.f,0.f},{0.f,0.f,0.f,0.f}};

    const int rrS = threadIdx.x >> 3, chS = threadIdx.x & 7;
    const size_t kbase = (size_t)(b * Sn) * 256 + kvh * 64;
    const size_t vbase = (size_t)(kvh * 64) * (size_t)ROWS + b * Sn;
    const int nblk = 2 * tile + 2;

    // prologue prefetch of KV block 0
    uint4 kr0 = *(const uint4*)(kb + kbase + (size_t)rrS * 256 + chS * 8);
    uint4 kr1 = *(const uint4*)(kb + kbase + (size_t)(rrS + 32) * 256 + chS * 8);
    uint4 vr0 = *(const uint4*)(vt + vbase + (size_t)rrS * ROWS + chS * 8);
    uint4 vr1 = *(const uint4*)(vt + vbase + (size_t)(rrS + 32) * ROWS + chS * 8);

    for (int kb_i = 0; kb_i < nblk; ++kb_i) {
        const int k0 = kb_i * 64;
        __syncthreads();                       // prev iter's LDS reads done
        *(uint4*)&Ks[rrS * 72 + chS * 8]        = kr0;
        *(uint4*)&Ks[(rrS + 32) * 72 + chS * 8] = kr1;
        *(uint4*)&Vs[rrS * 72 + chS * 8]        = vr0;
        *(uint4*)&Vs[(rrS + 32) * 72 + chS * 8] = vr1;
        __syncthreads();
        if (kb_i + 1 < nblk) {                 // prefetch next block (overlaps compute)
            int k0n = k0 + 64;
            kr0 = *(const uint4*)(kb + kbase + (size_t)(k0n + rrS) * 256 + chS * 8);
            kr1 = *(const uint4*)(kb + kbase + (size_t)(k0n + rrS + 32) * 256 + chS * 8);
            vr0 = *(const uint4*)(vt + vbase + (size_t)rrS * ROWS + k0n + chS * 8);
            vr1 = *(const uint4*)(vt + vbase + (size_t)(rrS + 32) * ROWS + k0n + chS * 8);
        }

        // QK^T for both q-frags
        f32x4 S0[4] = {}, S1[4] = {};
#pragma unroll
        for (int c = 0; c < 4; ++c) {
            bf16x8 kf0 = *(const bf16x8*)&Ks[(c * 16 + l15) * 72 + quad * 8];
            bf16x8 kf1 = *(const bf16x8*)&Ks[(c * 16 + l15) * 72 + 32 + quad * 8];
            S0[c] = mfma16(qf[0][0], kf0, S0[c]);
            S0[c] = mfma16(qf[0][1], kf1, S0[c]);
            S1[c] = mfma16(qf[1][0], kf0, S1[c]);
            S1[c] = mfma16(qf[1][1], kf1, S1[c]);
        }

#pragma unroll
        for (int f = 0; f < 2; ++f) {
            f32x4* S = f ? S1 : S0;
            const int qbF = q0 + w * 32 + f * 16;
            if (k0 + 63 > qbF) {               // diagonal-adjacent: mask
#pragma unroll
                for (int c = 0; c < 4; ++c) {
                    int key = k0 + c * 16 + l15;
#pragma unroll
                    for (int r = 0; r < 4; ++r)
                        if (key > qbF + quad * 4 + r) S[c][r] = -INFINITY;
                }
            }
#pragma unroll
            for (int c = 0; c < 4; ++c)
#pragma unroll
                for (int r = 0; r < 4; ++r) {
                    float p = exp2f(S[c][r] - mfix);
                    S[c][r] = p;
                    lsum[f][r] += p;
                }
            // pack (k, k+32) bf16 pairs (truncating) and store to LDS
            const int prow = w * 32 + f * 16 + quad * 4;
#pragma unroll
            for (int cp = 0; cp < 2; ++cp)
#pragma unroll
                for (int r = 0; r < 4; ++r) {
                    unsigned int pk = __builtin_amdgcn_perm(
                        __float_as_uint(S[cp + 2][r]), __float_as_uint(S[cp][r]),
                        0x07060302u);
                    PsD[(prow + r) * 36 + cp * 16 + l15] = pk;
                }
        }

        // PV for both q-frags
#pragma unroll
        for (int f = 0; f < 2; ++f) {
            const int prow = w * 32 + f * 16 + l15;
            unsigned int d[8];
            *(uint4*)&d[0] = *(const uint4*)&PsD[prow * 36 + quad * 8];
            *(uint4*)&d[4] = *(const uint4*)&PsD[prow * 36 + quad * 8 + 4];
            unsigned int lo[4], hi[4];
#pragma unroll
            for (int t = 0; t < 4; ++t) {
                lo[t] = __builtin_amdgcn_perm(d[2 * t + 1], d[2 * t], 0x05040100u);
                hi[t] = __builtin_amdgcn_perm(d[2 * t + 1], d[2 * t], 0x07060302u);
            }
            bf16x8 pf0 = *(const bf16x8*)lo;
            bf16x8 pf1 = *(const bf16x8*)hi;
#pragma unroll
            for (int dt = 0; dt < 4; ++dt) {
                bf16x8 vf0 = *(const bf16x8*)&Vs[(dt * 16 + l15) * 72 + quad * 8];
                bf16x8 vf1 = *(const bf16x8*)&Vs[(dt * 16 + l15) * 72 + 32 + quad * 8];
                Oacc[f][dt] = mfma16(pf0, vf0, Oacc[f][dt]);
                Oacc[f][dt] = mfma16(pf1, vf1, Oacc[f][dt]);
            }
        }
    }

    // deferred l-reduction + epilogue
#pragma unroll
    for (int f = 0; f < 2; ++f) {
#pragma unroll
        for (int m = 1; m <= 8; m <<= 1)
#pragma unroll
            for (int r = 0; r < 4; ++r)
                lsum[f][r] += __shfl_xor(lsum[f][r], m);
#pragma unroll
        for (int dt = 0; dt < 4; ++dt)
#pragma unroll
            for (int r = 0; r < 4; ++r) {
                size_t o = (size_t)(b * Sn + q0 + w * 32 + f * 16 + quad * 4 + r) * 1024
                         + h * 64 + dt * 16 + l15;
                ob[o] = f2bf(Oacc[f][dt][r] / lsum[f][r]);
            }
    }
}

// ---------------- LM head loss reductions (bf16 chunk) ----------------
__global__ void loss_init_kernel(float* __restrict__ m, float* __restrict__ s,
                                 float* __restrict__ tg) {
    int i = blockIdx.x * 256 + threadIdx.x;
    if (i < ROWS) { m[i] = -INFINITY; s[i] = 0.f; tg[i] = 0.f; }
}

__global__ __launch_bounds__(256)
void chunk_reduce_kernel(const ush* __restrict__ Cc, int Nc, int c0,
                         const int* __restrict__ y, float* __restrict__ m,
                         float* __restrict__ s, float* __restrict__ tg) {
    __shared__ float red[4];
    int r = blockIdx.x, tid = threadIdx.x;
    const ush* row = Cc + (size_t)r * VCHUNK;
    float v[16];
    float mx = -INFINITY;
#pragma unroll
    for (int t = 0; t < 16; ++t) {
        int j = tid + t * 256;
        v[t] = (j < Nc) ? b2f(row[j]) : -INFINITY;
        mx = fmaxf(mx, v[t]);
    }
    mx = block_max256(mx, red);
    float se = 0.f;
#pragma unroll
    for (int t = 0; t < 16; ++t)
        se += __expf(v[t] - mx);      // exp(-inf)=0 for padding
    se = block_sum256(se, red);
    if (tid == 0) {
        float mo = m[r];
        float mn = fmaxf(mo, mx);
        s[r] = s[r] * __expf(mo - mn) + se * __expf(mx - mn);
        m[r] = mn;
        int t = y[r] - c0;
        if (t >= 0 && t < Nc) tg[r] = b2f(row[t]);
    }
}

__global__ __launch_bounds__(256)
void loss_final_kernel(const float* __restrict__ m, const float* __restrict__ s,
                       const float* __restrict__ tg, float* __restrict__ out) {
    __shared__ float red[4];
    float part = 0.f;
    for (int r = threadIdx.x; r < ROWS; r += 256)
        part += m[r] + logf(s[r]) - tg[r];
    part = block_sum256(part, red);
    if (threadIdx.x == 0) out[0] = part * (1.f / ROWS);
}

// ---------------- host orchestration ----------------
extern "C" void kernel_launch(void* const* d_in, const int* in_sizes, int n_in,
                              void* d_out, int out_size, void* d_ws, size_t ws_size,
                              hipStream_t stream) {
    const int*   ids = (const int*)d_in[0];
    const int*   yv  = (const int*)d_in[1];
    const float* ue  = (const float*)d_in[2];
    const float* be  = (const float*)d_in[3];
    const float* Wq  = (const float*)d_in[4];
    const float* Wk  = (const float*)d_in[5];
    const float* Wv  = (const float*)d_in[6];
    const float* Wo  = (const float*)d_in[7];
    const float* qg  = (const float*)d_in[8];
    const float* asc = (const float*)d_in[9];
    const float* msc = (const float*)d_in[10];
    const float* rm  = (const float*)d_in[11];
    const float* Wf  = (const float*)d_in[12];
    const float* Wo2 = (const float*)d_in[13];
    const float* sw  = (const float*)d_in[14];
    (void)in_sizes; (void)n_in; (void)out_size; (void)ws_size;

    char* wsb = (char*)d_ws;
    size_t off = 0;
    auto alloc = [&](size_t bytes) {
        void* p = (void*)(wsb + off);
        off += ((bytes + 255) & ~size_t(255));
        return p;
    };
    // total ~296 MB (round-1's 312 MB layout fit; round-2's 443 MB crashed)
    float* h    = (float*)alloc((size_t)ROWS * Dm * 4);                // 16 MB
    float* h0   = (float*)alloc((size_t)ROWS * Dm * 4);                // 16 MB
    float* cosb = (float*)alloc((size_t)Sn * 32 * 4);
    float* sinb = (float*)alloc((size_t)Sn * 32 * 4);
    float* mrow = (float*)alloc(ROWS * 4);
    float* srow = (float*)alloc(ROWS * 4);
    float* tgv  = (float*)alloc(ROWS * 4);
    ush* skb  = (ush*)alloc((size_t)Ln * ROWS * Dm * 2);   // 48 MB bf16 skips
    ush* xnb  = (ush*)alloc((size_t)ROWS * Dm * 2);        // 8 MB
    ush* qkvb = (ush*)alloc((size_t)ROWS * 1536 * 2);      // 12 MB
    ush* qbf  = (ush*)alloc((size_t)ROWS * Dm * 2);        // 8 MB
    ush* kbf  = (ush*)alloc((size_t)ROWS * 256 * 2);       // 2 MB
    ush* vtb  = (ush*)alloc((size_t)256 * ROWS * 2);       // 2 MB
    ush* attb = (ush*)alloc((size_t)ROWS * Dm * 2);        // 8 MB
    ush* hidb = (ush*)alloc((size_t)ROWS * 3 * Dm * 2);    // 24 MB
    ush* wall = (ush*)alloc((size_t)Ln * 8704 * 1024 * 2); // 102 MB (all layers)
    ush* ueb  = (ush*)alloc((size_t)VPAD * 512 * 2);       // 49.2 MB
    // bf16 LM-head chunk (32 MB) aliases skb (skips dead by then)
    ush* chunk = skb;

    auto cvt = [&](const float* s, ush* d, size_t n) {
        int n4 = (int)(n / 4);
        cvt_bf16_kernel<<<(n4 + 255) / 256, 256, 0, stream>>>(s, d, n4);
    };

    // one-time conversions: all layers' weights persist in bf16
    for (int l = 0; l < Ln; ++l) {
        ush* wl = wall + (size_t)l * 8704 * 1024;
        cvt(Wq + (size_t)l * Dm * Dm,      wl,              (size_t)Dm * Dm);
        cvt(Wk + (size_t)l * 256 * Dm,     wl + 1024 * Dm,  (size_t)256 * Dm);
        cvt(Wv + (size_t)l * 256 * Dm,     wl + 1280 * Dm,  (size_t)256 * Dm);
        cvt(Wo + (size_t)l * Dm * Dm,      wl + 1536 * Dm,  (size_t)Dm * Dm);
        cvt(Wf + (size_t)l * 3 * Dm * Dm,  wl + 2560 * Dm,  (size_t)3 * Dm * Dm);
        cvt(Wo2 + (size_t)l * 3 * Dm * Dm, wl + 5632 * Dm,  (size_t)3 * Dm * Dm);
    }
    cvt(ue, ueb, (size_t)VSn * 512);
    zpad_kernel<<<((VPAD - VSn) * 512 + 255) / 256, 256, 0, stream>>>(
        ueb + (size_t)VSn * 512, (VPAD - VSn) * 512);

    rope_kernel<<<(Sn * 32 + 255) / 256, 256, 0, stream>>>(cosb, sinb);
    embed_kernel<<<ROWS, 256, 0, stream>>>(ids, ue, be, h, h0);

    auto run_block = [&](int l, ush* dup) {
        ush* wl    = wall + (size_t)l * 8704 * 1024;
        ush* wqkvb = wl;
        ush* wob   = wl + (size_t)1536 * 1024;
        ush* wfb   = wl + (size_t)2560 * 1024;
        ush* wo2b  = wl + (size_t)5632 * 1024;

        resmix_kernel<<<ROWS, 256, 0, stream>>>(h, h0, rm + (size_t)l * 2 * Dm, xnb);
        gemm_k<64, 0><<<dim3(ROWS / 64, 1536 / 128), 256, 0, stream>>>(
            xnb, wqkvb, qkvb, ROWS, 1536, Dm, Dm, Dm, 1536, nullptr, nullptr, nullptr);
        qknorm_rope_kernel<<<ROWS * (NHn + NKVn) / 4, 256, 0, stream>>>(
            qkvb, qbf, kbf, cosb, sinb, qg + (size_t)l * NHn);
        vtrans_kernel<<<dim3(ROWS / 32, 8), 256, 0, stream>>>(qkvb, vtb);
        attn_mfma_kernel<<<Bn * NHn * 16, 256, 0, stream>>>(
            qbf, kbf, vtb, attb, qg + (size_t)l * NHn);
        gemm_k<64, 3><<<dim3(ROWS / 64, Dm / 128), 256, 0, stream>>>(
            attb, wob, nullptr, ROWS, Dm, Dm, Dm, Dm, Dm,
            h, asc + (size_t)l * Dm, nullptr);
        rmsn_kernel<<<ROWS, 256, 0, stream>>>(h, xnb);
        gemm_k<128, 1><<<dim3(ROWS / 128, 3 * Dm / 128), 256, 0, stream>>>(
            xnb, wfb, hidb, ROWS, 3 * Dm, Dm, Dm, Dm, 3 * Dm, nullptr, nullptr, nullptr);
        gemm_k<64, 3><<<dim3(ROWS / 64, Dm / 128), 256, 0, stream>>>(
            hidb, wo2b, nullptr, ROWS, Dm, 3 * Dm, 3 * Dm, 3 * Dm, Dm,
            h, msc + (size_t)l * Dm, dup);
    };

    for (int l = 0; l < Ln; ++l)
        run_block(l, skb + (size_t)l * ROWS * Dm);
    for (int i = 0; i < Ln; ++i) {
        int j = Ln - 1 - i;
        skipadd_kernel<<<ROWS, 256, 0, stream>>>(h, skb + (size_t)j * ROWS * Dm,
                                                 sw + (size_t)i * Dm);
        run_block(j, nullptr);
    }

    // final norm + LM head (bf16 chunk aliases skb)
    rmsn_kernel<<<ROWS, 256, 0, stream>>>(h, xnb);
    loss_init_kernel<<<(ROWS + 255) / 256, 256, 0, stream>>>(mrow, srow, tgv);
    for (int c0 = 0; c0 < VSn; c0 += VCHUNK) {
        int Nc = (VSn - c0 < VCHUNK) ? (VSn - c0) : VCHUNK;
        int Ng = (VPAD - c0 < VCHUNK) ? (VPAD - c0) : VCHUNK;   // mult of 128
        gemm_k<128, 2><<<dim3(ROWS / 128, Ng / 128), 256, 0, stream>>>(
            xnb, ueb + (size_t)c0 * 512, chunk, ROWS, Ng, 512, Dm, 512, VCHUNK,
            nullptr, nullptr, nullptr);
        chunk_reduce_kernel<<<ROWS, 256, 0, stream>>>(chunk, Nc, c0, yv, mrow, srow, tgv);
    }
    loss_final_kernel<<<1, 256, 0, stream>>>(mrow, srow, tgv, (float*)d_out);
}

// Round 6
// 4210.166 us; speedup vs baseline: 7.3336x; 1.0427x over previous
//
#include <hip/hip_runtime.h>
#include <cstdint>
#include <cstddef>

// ---------------- constants (from reference) ----------------
constexpr int   Dm    = 1024;
constexpr int   NHn   = 16;
constexpr int   NKVn  = 4;
constexpr int   HDn   = 64;
constexpr int   Ln    = 6;
constexpr int   Sn    = 2048;
constexpr int   Bn    = 2;
constexpr int   ROWS  = Bn * Sn;          // 4096 token rows
constexpr int   VSn   = 50257;
constexpr int   HSn   = 4096;
constexpr float EPSF  = 1.1920929e-07f;
constexpr int   VCHUNK = 4096;            // vocab chunk for LM head
constexpr int   VPAD   = 50304;           // 393*128
constexpr float LOG2E  = 1.44269504f;

#define DEV __device__ __forceinline__

typedef __attribute__((ext_vector_type(8))) short bf16x8;
typedef __attribute__((ext_vector_type(4))) float f32x4;
using ush = unsigned short;

DEV ush f2bf(float f) {
    unsigned int u = __float_as_uint(f);
    u = (u + 0x7fffu + ((u >> 16) & 1u)) >> 16;
    return (ush)u;
}

DEV float b2f(ush v) {
    return __uint_as_float(((unsigned int)v) << 16);
}

DEV f32x4 mfma16(bf16x8 a, bf16x8 b, f32x4 c) {
    return __builtin_amdgcn_mfma_f32_16x16x32_bf16(a, b, c, 0, 0, 0);
}

DEV void llds16(const ush* g, ush* l) {
    __builtin_amdgcn_global_load_lds(
        (const __attribute__((address_space(1))) void*)g,
        (__attribute__((address_space(3))) void*)l, 16, 0, 0);
}

// ---------------- block reductions (256 threads = 4 waves) ----------------
DEV float block_sum256(float v, float* red) {
#pragma unroll
    for (int off = 32; off; off >>= 1) v += __shfl_xor(v, off);
    __syncthreads();
    if ((threadIdx.x & 63) == 0) red[threadIdx.x >> 6] = v;
    __syncthreads();
    return red[0] + red[1] + red[2] + red[3];
}

DEV float block_max256(float v, float* red) {
#pragma unroll
    for (int off = 32; off; off >>= 1) v = fmaxf(v, __shfl_xor(v, off));
    __syncthreads();
    if ((threadIdx.x & 63) == 0) red[threadIdx.x >> 6] = v;
    __syncthreads();
    return fmaxf(fmaxf(red[0], red[1]), fmaxf(red[2], red[3]));
}

// ---------------- rope tables ----------------
__global__ void rope_kernel(float* __restrict__ cb, float* __restrict__ sb) {
    int idx = blockIdx.x * 256 + threadIdx.x;
    if (idx >= Sn * 32) return;
    int t = idx >> 5, f = idx & 31;
    float freq = powf(10000.f, -(float)f * (1.f / 32.f));
    float ang  = (float)t * freq;
    cb[idx] = cosf(ang);
    sb[idx] = sinf(ang);
}

// ---------------- fp32 -> bf16 convert / zero pad ----------------
__global__ void cvt_bf16_kernel(const float* __restrict__ s, ush* __restrict__ d, int n4) {
    int i = blockIdx.x * 256 + threadIdx.x;
    if (i >= n4) return;
    float4 v = *(const float4*)(s + (size_t)i * 4);
    ushort4 o;
    o.x = f2bf(v.x); o.y = f2bf(v.y); o.z = f2bf(v.z); o.w = f2bf(v.w);
    *(ushort4*)(d + (size_t)i * 4) = o;
}

__global__ void zpad_kernel(ush* __restrict__ p, int n) {
    int i = blockIdx.x * 256 + threadIdx.x;
    if (i < n) p[i] = 0;
}

// ---------------- embedding + rmsn ----------------
__global__ __launch_bounds__(256)
void embed_kernel(const int* __restrict__ ids, const float* __restrict__ ue,
                  const float* __restrict__ be, float* __restrict__ h,
                  float* __restrict__ h0) {
    __shared__ float red[4];
    int r = blockIdx.x;
    int s = r % Sn;
    int id = ids[r];
    int prev = (s == 0) ? 0 : ids[r - 1];
    int bi = ((prev % HSn) * (VSn % HSn) % HSn + id % HSn) % HSn;
    int tid = threadIdx.x;
    float vals[4];
    float ss = 0.f;
#pragma unroll
    for (int t = 0; t < 4; ++t) {
        int j = tid + t * 256;
        float v = (j < 512) ? ue[(size_t)id * 512 + j]
                            : be[(size_t)bi * 512 + (j - 512)];
        vals[t] = v; ss += v * v;
    }
    ss = block_sum256(ss, red);
    float rinv = rsqrtf(ss * (1.f / Dm) + EPSF);
#pragma unroll
    for (int t = 0; t < 4; ++t) {
        int j = tid + t * 256;
        float v = vals[t] * rinv;
        h [(size_t)r * Dm + j] = v;
        h0[(size_t)r * Dm + j] = v;
    }
}

// ---------------- (optional skip add) + residual mix + rmsn -> bf16 ----------------
template<bool SKIP>
__global__ __launch_bounds__(256)
void resmix_kernel(float* __restrict__ h, const float* __restrict__ h0,
                   const float* __restrict__ rm0, ush* __restrict__ xnb,
                   const ush* __restrict__ skb, const float* __restrict__ sw) {
    __shared__ float red[4];
    int r = blockIdx.x, tid = threadIdx.x;
    const float* rm1 = rm0 + Dm;
    float vals[4]; float ss = 0.f;
#pragma unroll
    for (int t = 0; t < 4; ++t) {
        int j = tid + t * 256;
        size_t o = (size_t)r * Dm + j;
        float base = h[o];
        if (SKIP) base = fmaf(sw[j], b2f(skb[o]), base);
        float v = rm0[j] * base + rm1[j] * h0[o];
        vals[t] = v; ss += v * v;
        h[o] = v;
    }
    ss = block_sum256(ss, red);
    float rinv = rsqrtf(ss * (1.f / Dm) + EPSF);
#pragma unroll
    for (int t = 0; t < 4; ++t)
        xnb[(size_t)r * Dm + tid + t * 256] = f2bf(vals[t] * rinv);
}

// ---------------- standalone rmsn -> bf16 ----------------
__global__ __launch_bounds__(256)
void rmsn_kernel(const float* __restrict__ x, ush* __restrict__ out) {
    __shared__ float red[4];
    int r = blockIdx.x, tid = threadIdx.x;
    float vals[4]; float ss = 0.f;
#pragma unroll
    for (int t = 0; t < 4; ++t) {
        float v = x[(size_t)r * Dm + tid + t * 256];
        vals[t] = v; ss += v * v;
    }
    ss = block_sum256(ss, red);
    float rinv = rsqrtf(ss * (1.f / Dm) + EPSF);
#pragma unroll
    for (int t = 0; t < 4; ++t)
        out[(size_t)r * Dm + tid + t * 256] = f2bf(vals[t] * rinv);
}

// ---------------- bf16 MFMA GEMM: C(MxN) = A(MxK) @ B(NxK)^T ----------------
// TM in {64,128}. MODE 0: bf16 store  1: relu^2 bf16  2: 30*tanh(v/30) bf16
// MODE 3: residual add  h[row*ldc+col] += sc[col]*acc  (+ optional bf16 dup)
template<int TM, int MODE>
__global__ __launch_bounds__(256)
void gemm_k(const ush* __restrict__ A, const ush* __restrict__ B,
            ush* __restrict__ C, int M, int N, int K,
            int lda, int ldb, int ldc,
            float* __restrict__ hres, const float* __restrict__ sc,
            ush* __restrict__ dup) {
    __shared__ __align__(16) ush As[TM * 32];
    __shared__ __align__(16) ush Bs[128 * 32];
    const int m0 = blockIdx.x * TM, n0 = blockIdx.y * 128;
    const int tid  = threadIdx.x;
    const int w    = tid >> 6, lane = tid & 63;
    const int l15  = lane & 15, quad = lane >> 4;
    const int wr   = w >> 1, wc = w & 1;
    constexpr int NI = TM / 32;        // acc row-tiles per wave (4 or 2)

    const int srow = lane >> 2, sch = lane & 3;
    const ush* Ag;
    ush* AsW;
    if constexpr (TM == 128) {
        Ag  = A + (size_t)(m0 + w * 32 + srow) * lda + sch * 8;
        AsW = As + w * 1024;
    } else {
        Ag  = A + (size_t)(m0 + w * 16 + srow) * lda + sch * 8;
        AsW = As + w * 512;
    }
    const ush* Bg = B + (size_t)(n0 + w * 32 + srow) * ldb + sch * 8;
    ush* BsW = Bs + w * 1024;

    f32x4 acc[NI][4] = {};

    for (int k0 = 0; k0 < K; k0 += 32) {
        __syncthreads();
        llds16(Ag + k0, AsW);
        if constexpr (TM == 128) llds16(Ag + k0 + 16 * lda, AsW + 512);
        llds16(Bg + k0,            BsW);
        llds16(Bg + k0 + 16 * ldb, BsW + 512);
        __syncthreads();
        bf16x8 af[NI], bfv[4];
#pragma unroll
        for (int i = 0; i < NI; ++i)
            af[i] = *(const bf16x8*)&As[(wr * (TM / 2) + i * 16 + l15) * 32 + quad * 8];
#pragma unroll
        for (int j = 0; j < 4; ++j)
            bfv[j] = *(const bf16x8*)&Bs[(wc * 64 + j * 16 + l15) * 32 + quad * 8];
#pragma unroll
        for (int i = 0; i < NI; ++i)
#pragma unroll
            for (int j = 0; j < 4; ++j)
                acc[i][j] = mfma16(af[i], bfv[j], acc[i][j]);
    }

#pragma unroll
    for (int i = 0; i < NI; ++i) {
#pragma unroll
        for (int j = 0; j < 4; ++j) {
            int row = m0 + wr * (TM / 2) + i * 16 + quad * 4;
            int col = n0 + wc * 64 + j * 16 + l15;
#pragma unroll
            for (int r = 0; r < 4; ++r) {
                float v = acc[i][j][r];
                if (MODE == 1) { v = fmaxf(v, 0.f); v = v * v; }
                else if (MODE == 2) {
                    float ax = fabsf(v) * (1.f / 30.f);
                    float e  = __expf(-2.f * ax);
                    float t  = (1.f - e) / (1.f + e);
                    v = copysignf(t * 30.f, v);
                }
                if (MODE == 3) {
                    size_t o = (size_t)(row + r) * ldc + col;
                    float nv = fmaf(sc[col], v, hres[o]);
                    hres[o] = nv;
                    if (dup) dup[o] = f2bf(nv);
                } else {
                    C[(size_t)(row + r) * ldc + col] = f2bf(v);
                }
            }
        }
    }
}

// ---------------- fused q+k per-head rmsn + rope -> bf16 ----------------
__global__ __launch_bounds__(256)
void qknorm_rope_kernel(const ush* __restrict__ in,
                        ush* __restrict__ qout, ush* __restrict__ kout,
                        const float* __restrict__ cosb, const float* __restrict__ sinb,
                        const float* __restrict__ qg) {
    int idx  = blockIdx.x * 4 + (threadIdx.x >> 6);
    int lane = threadIdx.x & 63;
    int t, hh, in_off;
    ush* outp; int out_ld;
    bool isq = idx < ROWS * NHn;
    if (isq) { t = idx >> 4; hh = idx & 15; in_off = hh * 64; outp = qout; out_ld = 1024; }
    else { int i2 = idx - ROWS * NHn; t = i2 >> 2; hh = i2 & 3; in_off = 1024 + hh * 64; outp = kout; out_ld = 256; }
    int sidx = t % Sn;
    float x = b2f(in[(size_t)t * 1536 + in_off + lane]);
    float ss = x * x;
#pragma unroll
    for (int off = 32; off; off >>= 1) ss += __shfl_xor(ss, off);
    float xn = x * rsqrtf(ss * (1.f / HDn) + EPSF);
    float partner = __shfl_xor(xn, 32);
    int f = lane & 31;
    float c  = cosb[sidx * 32 + f];
    float sv = sinb[sidx * 32 + f];
    float o = (lane < 32) ? fmaf(xn, c, partner * sv)
                          : fmaf(xn, c, -partner * sv);
    if (isq) o *= qg[hh] * (0.125f * LOG2E);
    outp[(size_t)t * out_ld + hh * 64 + lane] = f2bf(o);
}

// ---------------- V transpose: bf16 [4096][1536] (cols 1280..1535) -> bf16 [256][4096] ----------------
__global__ __launch_bounds__(256)
void vtrans_kernel(const ush* __restrict__ in, ush* __restrict__ out) {
    __shared__ ush tile[32][33];
    int s0 = blockIdx.x * 32;
    int c0 = blockIdx.y * 32;
    int i = threadIdx.x >> 5;
    int j = threadIdx.x & 31;
#pragma unroll
    for (int k = 0; k < 4; ++k)
        tile[i + k * 8][j] = in[(size_t)(s0 + i + k * 8) * 1536 + 1280 + c0 + j];
    __syncthreads();
#pragma unroll
    for (int k = 0; k < 4; ++k)
        out[(size_t)(c0 + i + k * 8) * (size_t)ROWS + s0 + j] = tile[j][i + k * 8];
}

// ---------------- causal GQA flash attention, split-K, bf16 MFMA ----------------
// Static-max softmax => KV chunks combine by plain addition. Each block:
// (b, h, q-tile of 128 rows, 512-key chunk). Unnormalized O-partials (bf16)
// + l-partials (fp32) written to global; combine kernel normalizes.
// Per (b,h): tiles t=0..15, chunks c=0..(t>>2). 40 pairs -> grid 1280.
__global__ __launch_bounds__(256)
void attn_mfma_kernel(const ush* __restrict__ qb,
                      const ush* __restrict__ kb,
                      const ush* __restrict__ vt,
                      ush* __restrict__ opart,
                      float* __restrict__ lpart,
                      const float* __restrict__ qgl) {
    __shared__ __align__(16) ush Ks[64 * 72];
    __shared__ __align__(16) ush Vs[64 * 72];
    __shared__ __align__(16) unsigned int PsD[128 * 36];
    // decode (b, h, tile t, chunk c)
    const int pair = blockIdx.x % 40;
    const int bh   = blockIdx.x / 40;
    const int h    = bh & 15;
    const int b    = bh >> 4;
    const int g    = (pair >= 24) ? 3 : (pair >= 12) ? 2 : (pair >= 4) ? 1 : 0;
    const int off_p = pair - 2 * g * (g + 1);
    const int t    = 4 * g + off_p / (g + 1);
    const int c    = off_p % (g + 1);
    const int kvh  = h >> 2;
    const int w    = threadIdx.x >> 6, lane = threadIdx.x & 63;
    const int l15  = lane & 15, quad = lane >> 4;
    const int q0   = t * 128;
    const int k_lo = c * 512;
    const int k_hi_full = (t + 1) * 128;
    const int k_hi = (k_lo + 512 < k_hi_full) ? (k_lo + 512) : k_hi_full;
    const int nblk = (k_hi - k_lo) >> 6;
    const float mfix = 8.f * fabsf(qgl[h]) * LOG2E;

    // Q fragments: wave w covers q rows q0+w*32 .. +31 (frags f=0,1)
    bf16x8 qf[2][2];
    {
        size_t qr = (size_t)(b * Sn + q0 + w * 32 + l15) * 1024 + h * 64;
        qf[0][0] = *(const bf16x8*)(qb + qr + quad * 8);
        qf[0][1] = *(const bf16x8*)(qb + qr + 32 + quad * 8);
        qf[1][0] = *(const bf16x8*)(qb + qr + 16 * 1024 + quad * 8);
        qf[1][1] = *(const bf16x8*)(qb + qr + 16 * 1024 + 32 + quad * 8);
    }
    f32x4 Oacc[2][4] = {};
    float lsum[2][4] = {{0.f,0.f,0.f,0.f},{0.f,0.f,0.f,0.f}};

    const int rrS = threadIdx.x >> 3, chS = threadIdx.x & 7;
    const size_t kbase = (size_t)(b * Sn) * 256 + kvh * 64;
    const size_t vbase = (size_t)(kvh * 64) * (size_t)ROWS + b * Sn;

    // prologue prefetch of first KV block
    uint4 kr0 = *(const uint4*)(kb + kbase + (size_t)(k_lo + rrS) * 256 + chS * 8);
    uint4 kr1 = *(const uint4*)(kb + kbase + (size_t)(k_lo + rrS + 32) * 256 + chS * 8);
    uint4 vr0 = *(const uint4*)(vt + vbase + (size_t)rrS * ROWS + k_lo + chS * 8);
    uint4 vr1 = *(const uint4*)(vt + vbase + (size_t)(rrS + 32) * ROWS + k_lo + chS * 8);

    for (int kb_i = 0; kb_i < nblk; ++kb_i) {
        const int k0 = k_lo + kb_i * 64;
        __syncthreads();                       // prev iter's LDS reads done
        *(uint4*)&Ks[rrS * 72 + chS * 8]        = kr0;
        *(uint4*)&Ks[(rrS + 32) * 72 + chS * 8] = kr1;
        *(uint4*)&Vs[rrS * 72 + chS * 8]        = vr0;
        *(uint4*)&Vs[(rrS + 32) * 72 + chS * 8] = vr1;
        __syncthreads();
        if (kb_i + 1 < nblk) {                 // prefetch next block (overlaps compute)
            int k0n = k0 + 64;
            kr0 = *(const uint4*)(kb + kbase + (size_t)(k0n + rrS) * 256 + chS * 8);
            kr1 = *(const uint4*)(kb + kbase + (size_t)(k0n + rrS + 32) * 256 + chS * 8);
            vr0 = *(const uint4*)(vt + vbase + (size_t)rrS * ROWS + k0n + chS * 8);
            vr1 = *(const uint4*)(vt + vbase + (size_t)(rrS + 32) * ROWS + k0n + chS * 8);
        }

        // QK^T for both q-frags
        f32x4 S0[4] = {}, S1[4] = {};
#pragma unroll
        for (int cc = 0; cc < 4; ++cc) {
            bf16x8 kf0 = *(const bf16x8*)&Ks[(cc * 16 + l15) * 72 + quad * 8];
            bf16x8 kf1 = *(const bf16x8*)&Ks[(cc * 16 + l15) * 72 + 32 + quad * 8];
            S0[cc] = mfma16(qf[0][0], kf0, S0[cc]);
            S0[cc] = mfma16(qf[0][1], kf1, S0[cc]);
            S1[cc] = mfma16(qf[1][0], kf0, S1[cc]);
            S1[cc] = mfma16(qf[1][1], kf1, S1[cc]);
        }

#pragma unroll
        for (int f = 0; f < 2; ++f) {
            f32x4* S = f ? S1 : S0;
            const int qbF = q0 + w * 32 + f * 16;
            if (k0 + 63 > qbF) {               // diagonal-adjacent: mask
#pragma unroll
                for (int cc = 0; cc < 4; ++cc) {
                    int key = k0 + cc * 16 + l15;
#pragma unroll
                    for (int r = 0; r < 4; ++r)
                        if (key > qbF + quad * 4 + r) S[cc][r] = -INFINITY;
                }
            }
#pragma unroll
            for (int cc = 0; cc < 4; ++cc)
#pragma unroll
                for (int r = 0; r < 4; ++r) {
                    float p = exp2f(S[cc][r] - mfix);
                    S[cc][r] = p;
                    lsum[f][r] += p;
                }
            // pack (k, k+32) bf16 pairs (truncating) and store to LDS
            const int prow = w * 32 + f * 16 + quad * 4;
#pragma unroll
            for (int cp = 0; cp < 2; ++cp)
#pragma unroll
                for (int r = 0; r < 4; ++r) {
                    unsigned int pk = __builtin_amdgcn_perm(
                        __float_as_uint(S[cp + 2][r]), __float_as_uint(S[cp][r]),
                        0x07060302u);
                    PsD[(prow + r) * 36 + cp * 16 + l15] = pk;
                }
        }

        // PV for both q-frags
#pragma unroll
        for (int f = 0; f < 2; ++f) {
            const int prow = w * 32 + f * 16 + l15;
            unsigned int d[8];
            *(uint4*)&d[0] = *(const uint4*)&PsD[prow * 36 + quad * 8];
            *(uint4*)&d[4] = *(const uint4*)&PsD[prow * 36 + quad * 8 + 4];
            unsigned int lo[4], hi[4];
#pragma unroll
            for (int tt = 0; tt < 4; ++tt) {
                lo[tt] = __builtin_amdgcn_perm(d[2 * tt + 1], d[2 * tt], 0x05040100u);
                hi[tt] = __builtin_amdgcn_perm(d[2 * tt + 1], d[2 * tt], 0x07060302u);
            }
            bf16x8 pf0 = *(const bf16x8*)lo;
            bf16x8 pf1 = *(const bf16x8*)hi;
#pragma unroll
            for (int dt = 0; dt < 4; ++dt) {
                bf16x8 vf0 = *(const bf16x8*)&Vs[(dt * 16 + l15) * 72 + quad * 8];
                bf16x8 vf1 = *(const bf16x8*)&Vs[(dt * 16 + l15) * 72 + 32 + quad * 8];
                Oacc[f][dt] = mfma16(pf0, vf0, Oacc[f][dt]);
                Oacc[f][dt] = mfma16(pf1, vf1, Oacc[f][dt]);
            }
        }
    }

    // deferred l-reduction + unnormalized epilogue
#pragma unroll
    for (int f = 0; f < 2; ++f) {
#pragma unroll
        for (int m = 1; m <= 8; m <<= 1)
#pragma unroll
            for (int r = 0; r < 4; ++r)
                lsum[f][r] += __shfl_xor(lsum[f][r], m);
#pragma unroll
        for (int r = 0; r < 4; ++r) {
            int token = b * Sn + q0 + w * 32 + f * 16 + quad * 4 + r;
            if (l15 == 0)
                lpart[((size_t)c * ROWS + token) * NHn + h] = lsum[f][r];
#pragma unroll
            for (int dt = 0; dt < 4; ++dt)
                opart[((size_t)c * ROWS + token) * 1024 + h * 64 + dt * 16 + l15]
                    = f2bf(Oacc[f][dt][r]);
        }
    }
}

// ---------------- combine split-K partials: attb = sum(O)/sum(l) ----------------
__global__ __launch_bounds__(256)
void attn_combine_kernel(const ush* __restrict__ opart,
                         const float* __restrict__ lpart,
                         ush* __restrict__ attb) {
    int token = blockIdx.x;
    int j = threadIdx.x * 4;
    int head = j >> 6;
    int nc = ((token % Sn) >> 9) + 1;   // tile>>2 + 1
    float a0 = 0.f, a1 = 0.f, a2 = 0.f, a3 = 0.f, l = 0.f;
    for (int cc = 0; cc < nc; ++cc) {
        ushort4 o4 = *(const ushort4*)(opart + ((size_t)cc * ROWS + token) * 1024 + j);
        a0 += b2f(o4.x); a1 += b2f(o4.y); a2 += b2f(o4.z); a3 += b2f(o4.w);
        l  += lpart[((size_t)cc * ROWS + token) * NHn + head];
    }
    float rin = 1.f / l;
    ushort4 out;
    out.x = f2bf(a0 * rin); out.y = f2bf(a1 * rin);
    out.z = f2bf(a2 * rin); out.w = f2bf(a3 * rin);
    *(ushort4*)(attb + (size_t)token * 1024 + j) = out;
}

// ---------------- LM head loss reductions (bf16 chunk) ----------------
__global__ void loss_init_kernel(float* __restrict__ m, float* __restrict__ s,
                                 float* __restrict__ tg) {
    int i = blockIdx.x * 256 + threadIdx.x;
    if (i < ROWS) { m[i] = -INFINITY; s[i] = 0.f; tg[i] = 0.f; }
}

__global__ __launch_bounds__(256)
void chunk_reduce_kernel(const ush* __restrict__ Cc, int Nc, int c0,
                         const int* __restrict__ y, float* __restrict__ m,
                         float* __restrict__ s, float* __restrict__ tg) {
    __shared__ float red[4];
    int r = blockIdx.x, tid = threadIdx.x;
    const ush* row = Cc + (size_t)r * VCHUNK;
    float v[16];
    float mx = -INFINITY;
#pragma unroll
    for (int t = 0; t < 16; ++t) {
        int j = tid + t * 256;
        v[t] = (j < Nc) ? b2f(row[j]) : -INFINITY;
        mx = fmaxf(mx, v[t]);
    }
    mx = block_max256(mx, red);
    float se = 0.f;
#pragma unroll
    for (int t = 0; t < 16; ++t)
        se += __expf(v[t] - mx);      // exp(-inf)=0 for padding
    se = block_sum256(se, red);
    if (tid == 0) {
        float mo = m[r];
        float mn = fmaxf(mo, mx);
        s[r] = s[r] * __expf(mo - mn) + se * __expf(mx - mn);
        m[r] = mn;
        int t = y[r] - c0;
        if (t >= 0 && t < Nc) tg[r] = b2f(row[t]);
    }
}

__global__ __launch_bounds__(256)
void loss_final_kernel(const float* __restrict__ m, const float* __restrict__ s,
                       const float* __restrict__ tg, float* __restrict__ out) {
    __shared__ float red[4];
    float part = 0.f;
    for (int r = threadIdx.x; r < ROWS; r += 256)
        part += m[r] + logf(s[r]) - tg[r];
    part = block_sum256(part, red);
    if (threadIdx.x == 0) out[0] = part * (1.f / ROWS);
}

// ---------------- host orchestration ----------------
extern "C" void kernel_launch(void* const* d_in, const int* in_sizes, int n_in,
                              void* d_out, int out_size, void* d_ws, size_t ws_size,
                              hipStream_t stream) {
    const int*   ids = (const int*)d_in[0];
    const int*   yv  = (const int*)d_in[1];
    const float* ue  = (const float*)d_in[2];
    const float* be  = (const float*)d_in[3];
    const float* Wq  = (const float*)d_in[4];
    const float* Wk  = (const float*)d_in[5];
    const float* Wv  = (const float*)d_in[6];
    const float* Wo  = (const float*)d_in[7];
    const float* qg  = (const float*)d_in[8];
    const float* asc = (const float*)d_in[9];
    const float* msc = (const float*)d_in[10];
    const float* rm  = (const float*)d_in[11];
    const float* Wf  = (const float*)d_in[12];
    const float* Wo2 = (const float*)d_in[13];
    const float* sw  = (const float*)d_in[14];
    (void)in_sizes; (void)n_in; (void)out_size; (void)ws_size;

    char* wsb = (char*)d_ws;
    size_t off = 0;
    auto alloc = [&](size_t bytes) {
        void* p = (void*)(wsb + off);
        off += ((bytes + 255) & ~size_t(255));
        return p;
    };
    // total ~297 MB (round-1's 312 MB layout fit; round-2's 443 MB crashed)
    float* h    = (float*)alloc((size_t)ROWS * Dm * 4);                // 16 MB
    float* h0   = (float*)alloc((size_t)ROWS * Dm * 4);                // 16 MB
    float* cosb = (float*)alloc((size_t)Sn * 32 * 4);
    float* sinb = (float*)alloc((size_t)Sn * 32 * 4);
    float* mrow = (float*)alloc(ROWS * 4);
    float* srow = (float*)alloc(ROWS * 4);
    float* tgv  = (float*)alloc(ROWS * 4);
    float* lpart= (float*)alloc((size_t)4 * ROWS * NHn * 4);           // 1 MB
    ush* skb  = (ush*)alloc((size_t)Ln * ROWS * Dm * 2);   // 48 MB bf16 skips
    ush* xnb  = (ush*)alloc((size_t)ROWS * Dm * 2);        // 8 MB
    // qkvb + hidb contiguous: their 36 MB region is aliased by opart (32 MB)
    ush* qkvb = (ush*)alloc((size_t)ROWS * 1536 * 2);      // 12 MB
    ush* hidb = (ush*)alloc((size_t)ROWS * 3 * Dm * 2);    // 24 MB
    ush* opart = qkvb;                                     // alias (dead by attn time)
    ush* qbf  = (ush*)alloc((size_t)ROWS * Dm * 2);        // 8 MB
    ush* kbf  = (ush*)alloc((size_t)ROWS * 256 * 2);       // 2 MB
    ush* vtb  = (ush*)alloc((size_t)256 * ROWS * 2);       // 2 MB
    ush* attb = (ush*)alloc((size_t)ROWS * Dm * 2);        // 8 MB
    ush* wall = (ush*)alloc((size_t)Ln * 8704 * 1024 * 2); // 102 MB (all layers)
    ush* ueb  = (ush*)alloc((size_t)VPAD * 512 * 2);       // 49.2 MB
    // bf16 LM-head chunk (32 MB) aliases skb (skips dead by then)
    ush* chunk = skb;

    auto cvt = [&](const float* s, ush* d, size_t n) {
        int n4 = (int)(n / 4);
        cvt_bf16_kernel<<<(n4 + 255) / 256, 256, 0, stream>>>(s, d, n4);
    };

    // one-time conversions: all layers' weights persist in bf16
    for (int l = 0; l < Ln; ++l) {
        ush* wl = wall + (size_t)l * 8704 * 1024;
        cvt(Wq + (size_t)l * Dm * Dm,      wl,              (size_t)Dm * Dm);
        cvt(Wk + (size_t)l * 256 * Dm,     wl + 1024 * Dm,  (size_t)256 * Dm);
        cvt(Wv + (size_t)l * 256 * Dm,     wl + 1280 * Dm,  (size_t)256 * Dm);
        cvt(Wo + (size_t)l * Dm * Dm,      wl + 1536 * Dm,  (size_t)Dm * Dm);
        cvt(Wf + (size_t)l * 3 * Dm * Dm,  wl + 2560 * Dm,  (size_t)3 * Dm * Dm);
        cvt(Wo2 + (size_t)l * 3 * Dm * Dm, wl + 5632 * Dm,  (size_t)3 * Dm * Dm);
    }
    cvt(ue, ueb, (size_t)VSn * 512);
    zpad_kernel<<<((VPAD - VSn) * 512 + 255) / 256, 256, 0, stream>>>(
        ueb + (size_t)VSn * 512, (VPAD - VSn) * 512);

    rope_kernel<<<(Sn * 32 + 255) / 256, 256, 0, stream>>>(cosb, sinb);
    embed_kernel<<<ROWS, 256, 0, stream>>>(ids, ue, be, h, h0);

    auto run_block = [&](int l, ush* dup, const ush* skip, const float* swv) {
        ush* wl    = wall + (size_t)l * 8704 * 1024;
        ush* wqkvb = wl;
        ush* wob   = wl + (size_t)1536 * 1024;
        ush* wfb   = wl + (size_t)2560 * 1024;
        ush* wo2b  = wl + (size_t)5632 * 1024;

        if (skip)
            resmix_kernel<true><<<ROWS, 256, 0, stream>>>(
                h, h0, rm + (size_t)l * 2 * Dm, xnb, skip, swv);
        else
            resmix_kernel<false><<<ROWS, 256, 0, stream>>>(
                h, h0, rm + (size_t)l * 2 * Dm, xnb, nullptr, nullptr);
        gemm_k<64, 0><<<dim3(ROWS / 64, 1536 / 128), 256, 0, stream>>>(
            xnb, wqkvb, qkvb, ROWS, 1536, Dm, Dm, Dm, 1536, nullptr, nullptr, nullptr);
        qknorm_rope_kernel<<<ROWS * (NHn + NKVn) / 4, 256, 0, stream>>>(
            qkvb, qbf, kbf, cosb, sinb, qg + (size_t)l * NHn);
        vtrans_kernel<<<dim3(ROWS / 32, 8), 256, 0, stream>>>(qkvb, vtb);
        attn_mfma_kernel<<<Bn * NHn * 40, 256, 0, stream>>>(
            qbf, kbf, vtb, opart, lpart, qg + (size_t)l * NHn);
        attn_combine_kernel<<<ROWS, 256, 0, stream>>>(opart, lpart, attb);
        gemm_k<64, 3><<<dim3(ROWS / 64, Dm / 128), 256, 0, stream>>>(
            attb, wob, nullptr, ROWS, Dm, Dm, Dm, Dm, Dm,
            h, asc + (size_t)l * Dm, nullptr);
        rmsn_kernel<<<ROWS, 256, 0, stream>>>(h, xnb);
        gemm_k<128, 1><<<dim3(ROWS / 128, 3 * Dm / 128), 256, 0, stream>>>(
            xnb, wfb, hidb, ROWS, 3 * Dm, Dm, Dm, Dm, 3 * Dm, nullptr, nullptr, nullptr);
        gemm_k<64, 3><<<dim3(ROWS / 64, Dm / 128), 256, 0, stream>>>(
            hidb, wo2b, nullptr, ROWS, Dm, 3 * Dm, 3 * Dm, 3 * Dm, Dm,
            h, msc + (size_t)l * Dm, dup);
    };

    for (int l = 0; l < Ln; ++l)
        run_block(l, skb + (size_t)l * ROWS * Dm, nullptr, nullptr);
    for (int i = 0; i < Ln; ++i) {
        int j = Ln - 1 - i;
        run_block(j, nullptr, skb + (size_t)j * ROWS * Dm, sw + (size_t)i * Dm);
    }

    // final norm + LM head (bf16 chunk aliases skb)
    rmsn_kernel<<<ROWS, 256, 0, stream>>>(h, xnb);
    loss_init_kernel<<<(ROWS + 255) / 256, 256, 0, stream>>>(mrow, srow, tgv);
    for (int c0 = 0; c0 < VSn; c0 += VCHUNK) {
        int Nc = (VSn - c0 < VCHUNK) ? (VSn - c0) : VCHUNK;
        int Ng = (VPAD - c0 < VCHUNK) ? (VPAD - c0) : VCHUNK;   // mult of 128
        gemm_k<128, 2><<<dim3(ROWS / 128, Ng / 128), 256, 0, stream>>>(
            xnb, ueb + (size_t)c0 * 512, chunk, ROWS, Ng, 512, Dm, 512, VCHUNK,
            nullptr, nullptr, nullptr);
        chunk_reduce_kernel<<<ROWS, 256, 0, stream>>>(chunk, Nc, c0, yv, mrow, srow, tgv);
    }
    loss_final_kernel<<<1, 256, 0, stream>>>(mrow, srow, tgv, (float*)d_out);
}